// Round 18
// baseline (818.640 us; speedup 1.0000x reference)
//
#include <hip/hip_runtime.h>
#include <stdint.h>

#define B_ 2
#define L_ 2048
#define H_ 2048
#define NH_ 16
#define D_ 128
#define I_ 8192
#define M_ (B_*L_)

typedef unsigned short u16;
typedef __attribute__((ext_vector_type(8))) short bf16x8;
typedef __attribute__((ext_vector_type(4))) float f32x4;

__device__ __forceinline__ u16 f2bf(float f) {
  union { float f; uint32_t u; } c; c.f = f;
  return (u16)((c.u + 0x7fffu + ((c.u >> 16) & 1u)) >> 16);
}
__device__ __forceinline__ float bf2f(u16 h) {
  union { uint32_t u; float f; } c; c.u = ((uint32_t)h) << 16;
  return c.f;
}
// global -> LDS direct DMA, 16B/lane. LDS dest is wave-uniform base + lane*16.
__device__ __forceinline__ void gload16(const void* g, void* l) {
  __builtin_amdgcn_global_load_lds(
      (__attribute__((address_space(1))) void*)g,
      (__attribute__((address_space(3))) void*)l, 16, 0, 0);
}

// ---------------- fp32 -> bf16 conversion ----------------
__global__ void cvt_w(const float* __restrict__ src, u16* __restrict__ dst, int n4) {
  int i = blockIdx.x * blockDim.x + threadIdx.x;
  if (i >= n4) return;
  float4 v = ((const float4*)src)[i];
  ushort4 o;
  o.x = f2bf(v.x); o.y = f2bf(v.y); o.z = f2bf(v.z); o.w = f2bf(v.w);
  ((ushort4*)dst)[i] = o;
}

// ---- 2-region cvt, one launch ----
__global__ void cvt2(const float* __restrict__ s0, u16* __restrict__ d0, int n40,
                     const float* __restrict__ s1, u16* __restrict__ d1, int n41) {
  int i = blockIdx.x * blockDim.x + threadIdx.x;
  if (i < n40) {
    float4 v = ((const float4*)s0)[i];
    ushort4 o;
    o.x = f2bf(v.x); o.y = f2bf(v.y); o.z = f2bf(v.z); o.w = f2bf(v.w);
    ((ushort4*)d0)[i] = o;
  } else if (i < n40 + n41) {
    int j = i - n40;
    float4 v = ((const float4*)s1)[j];
    ushort4 o;
    o.x = f2bf(v.x); o.y = f2bf(v.y); o.z = f2bf(v.z); o.w = f2bf(v.w);
    ((ushort4*)d1)[j] = o;
  }
}

// ---- 3-region cvt (wq,wk,wv -> stacked dst), one launch ----
__global__ void cvt3(const float* __restrict__ s0, const float* __restrict__ s1,
                     const float* __restrict__ s2, u16* __restrict__ dst, int n4) {
  int i = blockIdx.x * blockDim.x + threadIdx.x;   // 3*n4 total
  int reg = i / n4, off = i % n4;
  const float* src = (reg == 0) ? s0 : (reg == 1) ? s1 : s2;
  float4 v = ((const float4*)src)[off];
  ushort4 o;
  o.x = f2bf(v.x); o.y = f2bf(v.y); o.z = f2bf(v.z); o.w = f2bf(v.w);
  ((ushort4*)(dst + (size_t)reg * H_ * H_))[off] = o;
}

// ---- split-K QKV finish: q/k/v = p0+p1, rope(q,k), scatter to (B,NH,L,D) ----
__global__ __launch_bounds__(256)
void qkv_finish(const u16* __restrict__ p0, const u16* __restrict__ p1,
                const float* __restrict__ cosT, const float* __restrict__ sinT,
                u16* __restrict__ qb, u16* __restrict__ kb, u16* __restrict__ vb) {
  int i = blockIdx.x * blockDim.x + threadIdx.x;  // B_*NH_*L_*64
  int d = i & 63;
  size_t row = (size_t)(i >> 6);          // (b*NH+h)*L + l
  int l = (int)(row & (L_ - 1));
  int h = (int)((row >> 11) & (NH_ - 1));
  int b = (int)(row >> 15);
  size_t bl = (size_t)b * L_ + l;
  const u16* r0 = p0 + bl * (3 * H_);
  const u16* r1 = p1 + bl * (3 * H_);
  int c = h * 128 + d;
  float cv = cosT[l * 64 + d], sv = sinT[l * 64 + d];
  float x1 = bf2f(r0[c]) + bf2f(r1[c]);
  float x2 = bf2f(r0[c + 64]) + bf2f(r1[c + 64]);
  u16* qp = qb + row * D_;
  qp[d]      = f2bf(x1 * cv - x2 * sv);
  qp[d + 64] = f2bf(x2 * cv + x1 * sv);
  x1 = bf2f(r0[c + 2048]) + bf2f(r1[c + 2048]);
  x2 = bf2f(r0[c + 2112]) + bf2f(r1[c + 2112]);
  u16* kp = kb + row * D_;
  kp[d]      = f2bf(x1 * cv - x2 * sv);
  kp[d + 64] = f2bf(x2 * cv + x1 * sv);
  u16* vp = vb + row * D_;
  vp[d]      = f2bf(bf2f(r0[c + 4096]) + bf2f(r1[c + 4096]));
  vp[d + 64] = f2bf(bf2f(r0[c + 4160]) + bf2f(r1[c + 4160]));
}

// ---------------- split-K partial reduce: out = p0 + p1 + res (fp32) --------
__global__ __launch_bounds__(256) void down_reduce(const u16* __restrict__ p0,
                                                   const u16* __restrict__ p1,
                                                   const float* __restrict__ res,
                                                   float* __restrict__ out, int n4) {
  int i = blockIdx.x * blockDim.x + threadIdx.x;
  if (i >= n4) return;
  ushort4 a = ((const ushort4*)p0)[i];
  ushort4 b = ((const ushort4*)p1)[i];
  float4 r = ((const float4*)res)[i];
  float4 o;
  o.x = bf2f(a.x) + bf2f(b.x) + r.x;
  o.y = bf2f(a.y) + bf2f(b.y) + r.y;
  o.z = bf2f(a.z) + bf2f(b.z) + r.z;
  o.w = bf2f(a.w) + bf2f(b.w) + r.w;
  ((float4*)out)[i] = o;
}

// ---- fused: x2 = p0+p1+res; h2 = rmsnorm(x2, w)  (one pass, block/row) ----
__global__ __launch_bounds__(256)
void reduce_rms(const u16* __restrict__ p0, const u16* __restrict__ p1,
                const float* __restrict__ res, const float* __restrict__ w,
                float* __restrict__ x2o, u16* __restrict__ h2o) {
  int row = blockIdx.x, t = threadIdx.x;
  size_t base = (size_t)row * H_;
  ushort4 a0 = ((const ushort4*)(p0 + base))[t * 2];
  ushort4 a1 = ((const ushort4*)(p0 + base))[t * 2 + 1];
  ushort4 b0 = ((const ushort4*)(p1 + base))[t * 2];
  ushort4 b1 = ((const ushort4*)(p1 + base))[t * 2 + 1];
  float4 r0 = ((const float4*)(res + base))[t * 2];
  float4 r1 = ((const float4*)(res + base))[t * 2 + 1];
  float4 v0, v1;
  v0.x = bf2f(a0.x) + bf2f(b0.x) + r0.x;
  v0.y = bf2f(a0.y) + bf2f(b0.y) + r0.y;
  v0.z = bf2f(a0.z) + bf2f(b0.z) + r0.z;
  v0.w = bf2f(a0.w) + bf2f(b0.w) + r0.w;
  v1.x = bf2f(a1.x) + bf2f(b1.x) + r1.x;
  v1.y = bf2f(a1.y) + bf2f(b1.y) + r1.y;
  v1.z = bf2f(a1.z) + bf2f(b1.z) + r1.z;
  v1.w = bf2f(a1.w) + bf2f(b1.w) + r1.w;
  ((float4*)(x2o + base))[t * 2] = v0;
  ((float4*)(x2o + base))[t * 2 + 1] = v1;
  float s = v0.x*v0.x + v0.y*v0.y + v0.z*v0.z + v0.w*v0.w
          + v1.x*v1.x + v1.y*v1.y + v1.z*v1.z + v1.w*v1.w;
  for (int m = 1; m < 64; m <<= 1) s += __shfl_xor(s, m);
  __shared__ float sm[4];
  if ((t & 63) == 0) sm[t >> 6] = s;
  __syncthreads();
  float tot = sm[0] + sm[1] + sm[2] + sm[3];
  float rs = rsqrtf(tot / (float)H_ + 1e-6f);
  const float4* wr = (const float4*)w;
  float4 w0 = wr[t * 2], w1 = wr[t * 2 + 1];
  ushort4 o0, o1;
  o0.x = f2bf(v0.x * rs * w0.x); o0.y = f2bf(v0.y * rs * w0.y);
  o0.z = f2bf(v0.z * rs * w0.z); o0.w = f2bf(v0.w * rs * w0.w);
  o1.x = f2bf(v1.x * rs * w1.x); o1.y = f2bf(v1.y * rs * w1.y);
  o1.z = f2bf(v1.z * rs * w1.z); o1.w = f2bf(v1.w * rs * w1.w);
  ((ushort4*)(h2o + base))[t * 2] = o0;
  ((ushort4*)(h2o + base))[t * 2 + 1] = o1;
}

// ---------------- RMSNorm: one block per row ----------------
__global__ __launch_bounds__(256) void rmsnorm_k(const float* __restrict__ x,
                                                 const float* __restrict__ w,
                                                 u16* __restrict__ out) {
  int row = blockIdx.x;
  int t = threadIdx.x;
  const float4* xr = (const float4*)(x + (size_t)row * H_);
  float4 a = xr[t * 2], b = xr[t * 2 + 1];
  float s = a.x*a.x + a.y*a.y + a.z*a.z + a.w*a.w
          + b.x*b.x + b.y*b.y + b.z*b.z + b.w*b.w;
  for (int m = 1; m < 64; m <<= 1) s += __shfl_xor(s, m);
  __shared__ float sm[4];
  if ((t & 63) == 0) sm[t >> 6] = s;
  __syncthreads();
  float tot = sm[0] + sm[1] + sm[2] + sm[3];
  float rs = rsqrtf(tot / (float)H_ + 1e-6f);
  const float4* wr = (const float4*)w;
  float4 w0 = wr[t * 2], w1 = wr[t * 2 + 1];
  ushort4 o0, o1;
  o0.x = f2bf(a.x * rs * w0.x); o0.y = f2bf(a.y * rs * w0.y);
  o0.z = f2bf(a.z * rs * w0.z); o0.w = f2bf(a.w * rs * w0.w);
  o1.x = f2bf(b.x * rs * w1.x); o1.y = f2bf(b.y * rs * w1.y);
  o1.z = f2bf(b.z * rs * w1.z); o1.w = f2bf(b.w * rs * w1.w);
  ushort4* orow = (ushort4*)(out + (size_t)row * H_);
  orow[t * 2] = o0; orow[t * 2 + 1] = o1;
}

// ---------------- RoPE tables ----------------
__global__ void rope_tab(float* __restrict__ cosT, float* __restrict__ sinT,
                         const int* __restrict__ offp) {
  int i = blockIdx.x * blockDim.x + threadIdx.x;  // L_*64
  int d = i & 63, l = i >> 6;
  float inv = powf(10000.0f, -(float)d / 64.0f);
  float ang = (float)(l + *offp) * inv;
  cosT[i] = cosf(ang);
  sinT[i] = sinf(ang);
}

// ---------------- RoPE apply, in-place on (B,NH,L,D) bf16 (fallback) --------
__global__ void rope_apply(u16* __restrict__ qk, const float* __restrict__ cosT,
                           const float* __restrict__ sinT) {
  int i = blockIdx.x * blockDim.x + threadIdx.x;  // B_*NH_*L_*64
  int d = i & 63;
  size_t row = (size_t)(i >> 6);
  int l = (int)(row & (L_ - 1));
  u16* p = qk + row * D_;
  float x1 = bf2f(p[d]), x2 = bf2f(p[d + 64]);
  float c = cosT[l * 64 + d], s = sinT[l * 64 + d];
  p[d]      = f2bf(x1 * c - x2 * s);
  p[d + 64] = f2bf(x2 * c + x1 * s);
}

// ---------------- V transpose: (B,NH,L,D) -> (B,NH,D,L) ----------------
__global__ __launch_bounds__(256) void vtrans_k(const u16* __restrict__ v,
                                                u16* __restrict__ vt) {
  __shared__ u16 tile[64][65];
  int l0 = blockIdx.x * 64, d0 = blockIdx.y * 64;
  size_t base = (size_t)blockIdx.z * L_ * D_;
  int t = threadIdx.x;
  int tr = t >> 3, tc = (t & 7) * 8;
  #pragma unroll
  for (int it = 0; it < 2; ++it) {
    int r = tr + it * 32;
    const u16* src = v + base + (size_t)(l0 + r) * D_ + d0 + tc;
    ushort4 u0 = ((const ushort4*)src)[0], u1 = ((const ushort4*)src)[1];
    tile[r][tc + 0] = u0.x; tile[r][tc + 1] = u0.y;
    tile[r][tc + 2] = u0.z; tile[r][tc + 3] = u0.w;
    tile[r][tc + 4] = u1.x; tile[r][tc + 5] = u1.y;
    tile[r][tc + 6] = u1.z; tile[r][tc + 7] = u1.w;
  }
  __syncthreads();
  #pragma unroll
  for (int it = 0; it < 2; ++it) {
    int r = tr + it * 32;
    u16* dst = vt + base + (size_t)(d0 + r) * L_ + l0 + tc;
    ushort4 o0, o1;
    o0.x = tile[tc + 0][r]; o0.y = tile[tc + 1][r];
    o0.z = tile[tc + 2][r]; o0.w = tile[tc + 3][r];
    o1.x = tile[tc + 4][r]; o1.y = tile[tc + 5][r];
    o1.z = tile[tc + 6][r]; o1.w = tile[tc + 7][r];
    ((ushort4*)dst)[0] = o0; ((ushort4*)dst)[1] = o1;
  }
}

#define EPI_SILU 1
#define EPI_MUL 2
#define EPI_PART 4
#define EPI_QKV3 5
#define EPI_GLU 6

// ---------------- GEMM 256x256 8-wave quadrant-phased (r9 structure) ---------
// FROZEN K-loop (r6/r8/r10 schedule variants null at MfmaUtil ~30-45%).
// 512 thr = 8 waves; BK=64; LDS 128KB dbuf; vmcnt(4) counted waits; XOR
// swizzle both-sides (rule #21); column-major wg->(m,n). NO tail-cvt (r15).
template <int EPI>
__global__ __launch_bounds__(512, 2)
void gemm256(const u16* __restrict__ A, const u16* __restrict__ Bw,
             int M, int N, int K, int nk,
             u16* __restrict__ outb, u16* __restrict__ outb2,
             const u16* __restrict__ Bw2) {
  __shared__ __attribute__((aligned(16))) u16 Asm[2][2][8192];
  __shared__ __attribute__((aligned(16))) u16 Bsm[2][2][8192];
  int tid = threadIdx.x;
  int wid = tid >> 6, lane = tid & 63;
  int r16 = lane & 15, g4 = lane >> 4;
  // bijective XCD swizzle (m204)
  int nwg = gridDim.x, bid = blockIdx.x;
  int q8 = nwg >> 3, r8 = nwg & 7, xcd = bid & 7, loc = bid >> 3;
  int wgall = (xcd < r8 ? xcd * (q8 + 1) : r8 * (q8 + 1) + (xcd - r8) * q8) + loc;
  int nwg_geo = (M >> 8) * ((EPI == EPI_GLU) ? (N >> 7) : (N >> 8));
  int ks = wgall / nwg_geo;     // split-K slice (EPI_PART)
  int wg = wgall % nwg_geo;
  int MX = M >> 8;
  int m0 = (wg % MX) * 256;     // column-major: m fastest
  int n0 = (wg / MX) * ((EPI == EPI_GLU) ? 128 : 256);
  const char* Ab = (const char*)(A + (size_t)ks * nk * 64);
  const char* Bb = (const char*)(Bw + (size_t)ks * nk * 64);
  const char* Bb2 = (const char*)Bw2;
  u16* ob = (EPI == EPI_PART && ks) ? outb2 : outb;

  f32x4 acc[2][2][4][2] = {};
  bf16x8 afr[4][2];      // A frags for current qm
  bf16x8 bfr[2][2][2];   // B frags [qn][nf][kk], both qn held

  // stage half sel of tile kt1: 0:A-h0 1:B-h0 2:B-h1 3:A-h1
  auto STAGE = [&](int kt1, int sel) {
    if (kt1 >= nk) return;
    int buf = kt1 & 1;
    int k0 = kt1 << 6;
    const char* gb; char* lb; int row0;
    if (sel == 0)      { gb = Ab; row0 = m0;       lb = (char*)&Asm[buf][0][0]; }
    else if (sel == 3) { gb = Ab; row0 = m0 + 128; lb = (char*)&Asm[buf][1][0]; }
    else if (sel == 1) { gb = Bb; row0 = n0;       lb = (char*)&Bsm[buf][0][0]; }
    else               { gb = (EPI == EPI_GLU) ? Bb2 : Bb;
                         row0 = (EPI == EPI_GLU) ? n0 : n0 + 128;
                         lb = (char*)&Bsm[buf][1][0]; }
    #pragma unroll
    for (int j = 0; j < 2; ++j) {
      int p = j * 8192 + wid * 1024 + lane * 16;
      int r = p >> 7;
      int cb = (p & 127) ^ ((r & 7) << 4);
      gload16(gb + ((size_t)(row0 + r) * K + k0) * 2 + cb,
              lb + j * 8192 + wid * 1024);
    }
  };

  // prologue: tile 0, order A0,B0,B1,A1 (8 loads in flight)
  STAGE(0, 0); STAGE(0, 1); STAGE(0, 2); STAGE(0, 3);

  const int QM[4] = {0, 0, 1, 1};
  const int QN[4] = {0, 1, 1, 0};

  for (int kt = 0; kt < nk; ++kt) {
    int cur = kt & 1;
    #pragma unroll
    for (int ph = 0; ph < 4; ++ph) {
      if (ph < 3) {
        __builtin_amdgcn_sched_barrier(0);
        asm volatile("s_waitcnt vmcnt(4)" ::: "memory");
      }
      __builtin_amdgcn_s_barrier();
      __builtin_amdgcn_sched_barrier(0);
      const int qm = QM[ph], qn = QN[ph];
      if (ph == 0 || ph == 2) {            // (re)load A frags for this qm
        const char* Ah = (const char*)&Asm[cur][qm][0];
        #pragma unroll
        for (int mf = 0; mf < 4; ++mf) {
          int R = (wid >> 2) * 64 + mf * 16 + r16;
          int sw = (R & 7) << 4;
          afr[mf][0] = *(const bf16x8*)(Ah + R * 128 + ((g4 * 16) ^ sw));
          afr[mf][1] = *(const bf16x8*)(Ah + R * 128 + ((64 + g4 * 16) ^ sw));
        }
      }
      if (ph == 0 || ph == 1) {            // load B frags for this qn
        const char* Bh = (const char*)&Bsm[cur][qn][0];
        #pragma unroll
        for (int nf = 0; nf < 2; ++nf) {
          int R = (wid & 3) * 32 + nf * 16 + r16;
          int sw = (R & 7) << 4;
          bfr[qn][nf][0] = *(const bf16x8*)(Bh + R * 128 + ((g4 * 16) ^ sw));
          bfr[qn][nf][1] = *(const bf16x8*)(Bh + R * 128 + ((64 + g4 * 16) ^ sw));
        }
      }
      STAGE(kt + 1, ph);                    // next tile, one half per phase
      __builtin_amdgcn_s_setprio(1);
      #pragma unroll
      for (int mf = 0; mf < 4; ++mf)
        #pragma unroll
        for (int nf = 0; nf < 2; ++nf)
          #pragma unroll
          for (int kk = 0; kk < 2; ++kk)
            acc[qm][qn][mf][nf] = __builtin_amdgcn_mfma_f32_16x16x32_bf16(
                afr[mf][kk], bfr[qn][nf][kk], acc[qm][qn][mf][nf], 0, 0, 0);
      __builtin_amdgcn_s_setprio(0);
    }
  }
  // epilogue
  if (EPI == EPI_GLU) {
    #pragma unroll
    for (int qm = 0; qm < 2; ++qm)
      #pragma unroll
      for (int mf = 0; mf < 4; ++mf)
        #pragma unroll
        for (int nf = 0; nf < 2; ++nf)
          #pragma unroll
          for (int rr = 0; rr < 4; ++rr) {
            int row = m0 + qm * 128 + (wid >> 2) * 64 + mf * 16 + g4 * 4 + rr;
            int col = n0 + (wid & 3) * 32 + nf * 16 + r16;
            float g = acc[qm][0][mf][nf][rr];
            float u = acc[qm][1][mf][nf][rr];
            float sg = g / (1.0f + __expf(-g));
            outb[(size_t)row * N + col] = f2bf(sg * u);
          }
    return;
  }
  #pragma unroll
  for (int qm = 0; qm < 2; ++qm)
    #pragma unroll
    for (int qn = 0; qn < 2; ++qn)
      #pragma unroll
      for (int mf = 0; mf < 4; ++mf)
        #pragma unroll
        for (int nf = 0; nf < 2; ++nf)
          #pragma unroll
          for (int rr = 0; rr < 4; ++rr) {
            int row = m0 + qm * 128 + (wid >> 2) * 64 + mf * 16 + g4 * 4 + rr;
            int col = n0 + qn * 128 + (wid & 3) * 32 + nf * 16 + r16;
            float val = acc[qm][qn][mf][nf][rr];
            if (EPI == EPI_SILU) {
              ob[(size_t)row * N + col] = f2bf(val / (1.0f + __expf(-val)));
            } else if (EPI == EPI_MUL) {
              float g = bf2f(ob[(size_t)row * N + col]);
              ob[(size_t)row * N + col] = f2bf(g * val);
            } else if (EPI == EPI_PART) {
              ob[(size_t)row * N + col] = f2bf(val);
            } else if (EPI == EPI_QKV3) {
              int which = col >> 11, within = col & 2047;
              int hh = within >> 7, d = within & 127;
              int bb = row >> 11, l = row & 2047;
              ob[(size_t)which * M_ * H_ +
                 ((((size_t)bb * NH_ + hh) * L_ + l) << 7) + d] = f2bf(val);
            }
          }
}

// ---------------- Flash attention (causal), QBLK=64, K/V dbuf + defer-max ----
// T13 defer-max (THR=8): skip O/lsum rescale when __all(rm <= mrow+8);
// P bounded by e^8 (bf16-safe), lsum fp32. Guide m214v23: +5%, data-indep.
__global__ __launch_bounds__(256)
void flash_attn(const u16* __restrict__ q, const u16* __restrict__ k,
                const u16* __restrict__ vt, u16* __restrict__ out) {
  __shared__ __attribute__((aligned(16))) u16 Kt[2][64 * 128];
  __shared__ __attribute__((aligned(16))) u16 Vt[2][128 * 64];
  __shared__ __attribute__((aligned(16))) u16 Pl[4][16 * 64];
  int tid = threadIdx.x, w = tid >> 6, lane = tid & 63;
  int r16 = lane & 15, g4 = lane >> 4;
  int b = blockIdx.z, h = blockIdx.y;
  int qt = gridDim.x - 1 - blockIdx.x;   // longest blocks dispatch first
  int q0 = qt * 64;
  size_t bh = (size_t)b * NH_ + h;
  const char* qb = (const char*)(q + bh * L_ * D_);
  const char* kb = (const char*)(k + bh * L_ * D_);
  const char* vb = (const char*)(vt + bh * D_ * L_);
  int qrow = q0 + w * 16 + r16;
  bf16x8 qf[4];
  #pragma unroll
  for (int c = 0; c < 4; ++c)
    qf[c] = *(const bf16x8*)(qb + ((size_t)qrow * 128 + c * 32 + g4 * 8) * 2);
  f32x4 oacc[8] = {};
  float mrow[4], lsum[4];
  #pragma unroll
  for (int r = 0; r < 4; ++r) { mrow[r] = -3.0e38f; lsum[r] = 0.f; }
  int myq = q0 + w * 16 + g4 * 4;
  int ntiles = qt + 1;
  int rsw = (r16 & 7) << 4;
  const float sc = 0.08838834764831845f;

  auto STAGEKV = [&](int t, int buf) {
    if (t >= ntiles) return;
    int kv0 = t * 64;
    #pragma unroll
    for (int i = 0; i < 4; ++i) {
      int uoff = i * 4096 + w * 1024;
      int lin = uoff + lane * 16;
      int krow = lin >> 8;
      int kcol = (lin & 255) ^ ((krow & 7) << 4);
      gload16(kb + (size_t)(kv0 + krow) * 256 + kcol,
              (char*)&Kt[buf][0] + uoff);
      int vrow = lin >> 7;
      int vcol = (lin & 127) ^ ((vrow & 7) << 4);
      gload16(vb + (size_t)vrow * (L_ * 2) + kv0 * 2 + vcol,
              (char*)&Vt[buf][0] + uoff);
    }
  };

  STAGEKV(0, 0);
  __syncthreads();   // implicit vmcnt(0) drain before first compute

  for (int t = 0; t < ntiles; ++t) {
    int buf = t & 1;
    int kv0 = t * 64;
    STAGEKV(t + 1, buf ^ 1);   // prefetch next tile; lands during compute
    const char* Kb = (const char*)&Kt[buf][0];
    const char* Vb = (const char*)&Vt[buf][0];
    // S = Q K^T
    f32x4 s[4] = {};
    __builtin_amdgcn_s_setprio(1);
    #pragma unroll
    for (int c = 0; c < 4; ++c) {
      #pragma unroll
      for (int n = 0; n < 4; ++n) {
        bf16x8 kf = *(const bf16x8*)(Kb + (n * 16 + r16) * 256
                                     + ((c * 64 + g4 * 16) ^ rsw));
        s[n] = __builtin_amdgcn_mfma_f32_16x16x32_bf16(qf[c], kf, s[n], 0, 0, 0);
      }
    }
    __builtin_amdgcn_s_setprio(0);
    // scale + causal mask + online softmax (defer-max, THR=8)
    #pragma unroll
    for (int r = 0; r < 4; ++r) {
      float rm = -3.0e38f;
      #pragma unroll
      for (int n = 0; n < 4; ++n) {
        float v = s[n][r] * sc;
        int kvi = kv0 + n * 16 + r16;
        if (kvi > myq + r) v = -3.0e38f;
        s[n][r] = v;
        rm = fmaxf(rm, v);
      }
      rm = fmaxf(rm, __shfl_xor(rm, 1));
      rm = fmaxf(rm, __shfl_xor(rm, 2));
      rm = fmaxf(rm, __shfl_xor(rm, 4));
      rm = fmaxf(rm, __shfl_xor(rm, 8));
      bool nosc = __all(rm <= mrow[r] + 8.0f);   // wave-uniform
      if (!nosc) {
        float mnew = fmaxf(mrow[r], rm);
        float alpha = __expf(mrow[r] - mnew);
        mrow[r] = mnew;
        lsum[r] *= alpha;
        #pragma unroll
        for (int nf = 0; nf < 8; ++nf) oacc[nf][r] *= alpha;
      }
      float mm = mrow[r];
      int prow = g4 * 4 + r;
      int psw = (prow & 7) << 3;
      #pragma unroll
      for (int n = 0; n < 4; ++n) {
        float pv = __expf(s[n][r] - mm);
        lsum[r] += pv;
        Pl[w][prow * 64 + ((n * 16 + r16) ^ psw)] = f2bf(pv);
      }
    }
    // wave-internal LDS visibility fence (guide rule #18)
    asm volatile("s_waitcnt lgkmcnt(0)" ::: "memory");
    __builtin_amdgcn_sched_barrier(0);
    // O += P V
    __builtin_amdgcn_s_setprio(1);
    #pragma unroll
    for (int kc = 0; kc < 2; ++kc) {
      bf16x8 pf = *(const bf16x8*)((const char*)&Pl[w][0] + r16 * 128
                                   + ((kc * 64 + g4 * 16) ^ rsw));
      #pragma unroll
      for (int nf = 0; nf < 8; ++nf) {
        bf16x8 vf = *(const bf16x8*)(Vb + (nf * 16 + r16) * 128
                                     + ((kc * 64 + g4 * 16) ^ rsw));
        oacc[nf] = __builtin_amdgcn_mfma_f32_16x16x32_bf16(pf, vf, oacc[nf], 0, 0, 0);
      }
    }
    __builtin_amdgcn_s_setprio(0);
    __syncthreads();   // drains prefetch (vmcnt(0)) + publishes buf^1
  }
  #pragma unroll
  for (int r = 0; r < 4; ++r) {
    float l = lsum[r];
    l += __shfl_xor(l, 1); l += __shfl_xor(l, 2);
    l += __shfl_xor(l, 4); l += __shfl_xor(l, 8);
    float inv = 1.0f / l;
    size_t orow = ((size_t)b * L_ + (myq + r)) * H_ + h * D_;
    #pragma unroll
    for (int nf = 0; nf < 8; ++nf)
      out[orow + nf * 16 + r16] = f2bf(oacc[nf][r] * inv);
  }
}

// ---------------- host orchestration ----------------
extern "C" void kernel_launch(void* const* d_in, const int* in_sizes, int n_in,
                              void* d_out, int out_size, void* d_ws, size_t ws_size,
                              hipStream_t stream) {
  (void)in_sizes; (void)n_in; (void)out_size;
  const float* x    = (const float*)d_in[0];
  const float* ln1w = (const float*)d_in[1];
  const float* ln2w = (const float*)d_in[2];
  const float* wq   = (const float*)d_in[3];
  const float* wk   = (const float*)d_in[4];
  const float* wv   = (const float*)d_in[5];
  const float* wo   = (const float*)d_in[6];
  const float* wg   = (const float*)d_in[7];
  const float* wu   = (const float*)d_in[8];
  const float* wd   = (const float*)d_in[9];
  const int*   offp = (const int*)d_in[11];
  float* out = (float*)d_out;

  char* p = (char*)d_ws;
  auto alloc = [&](size_t bytes) {
    char* r = p;
    p += (bytes + 255) & ~(size_t)255;
    return r;
  };
  const size_t HH = (size_t)H_ * H_, IH = (size_t)I_ * H_;
  u16* wbuf = (u16*)alloc(IH * 2);                  // 32 MB, reused
  u16* h1   = (u16*)alloc((size_t)M_ * H_ * 2);     // 16 MB (h2; down partial 0)
  u16* qb   = (u16*)alloc((size_t)M_ * H_ * 2);     // 16 MB (gateb after attn)
  u16* kb   = (u16*)alloc((size_t)M_ * H_ * 2);     // 16 MB (WO partial 0)
  u16* vb   = (u16*)alloc((size_t)M_ * H_ * 2);     // 16 MB (WO partial 1)
  u16* vtb  = (u16*)alloc((size_t)M_ * H_ * 2);     // 16 MB
  u16* attn = (u16*)alloc((size_t)M_ * H_ * 2);     // 16 MB (down partial 1)
  float* x2 = (float*)alloc((size_t)M_ * H_ * 4);   // 32 MB
  float* cosT = (float*)alloc((size_t)L_ * 64 * 4);
  float* sinT = (float*)alloc((size_t)L_ * 64 * 4);
  u16* h2    = h1;   // h1 dead after QKV GEMM
  u16* gateb = qb;   // qb..vtb region dead after flash_attn / WO
  size_t used_base = (size_t)(p - (char*)d_ws);
  size_t MB96 = 2 * (((size_t)M_ * 3 * H_ * 2 + 255) & ~(size_t)255);
  bool tier1 = (used_base + MB96) <= ws_size;
  bool tier2 = !tier1 && (used_base + IH * 2) <= ws_size;
  u16 *p0 = nullptr, *p1 = nullptr, *wu_b = nullptr, *wd_b = nullptr;
  if (tier1) {
    p0 = (u16*)alloc((size_t)M_ * 3 * H_ * 2);      // 48 MB
    p1 = (u16*)alloc((size_t)M_ * 3 * H_ * 2);      // 48 MB
    wu_b = p0;    // free after qkv_finish
    wd_b = p1;    // free after qkv_finish (48MB >= 32MB needed)
  } else if (tier2) {
    wu_b = (u16*)alloc(IH * 2);
  }

  const int nHH4 = (int)(HH / 4), nIH4 = (int)(IH / 4);
  const int MH4 = M_ * H_ / 4;

  rmsnorm_k<<<M_, 256, 0, stream>>>(x, ln1w, h1);
  rope_tab<<<(L_ * 64) / 256, 256, 0, stream>>>(cosT, sinT, offp);

  // QKV weights -> wbuf (stacked), one launch
  cvt3<<<3 * nHH4 / 256, 256, 0, stream>>>(wq, wk, wv, wbuf, nHH4);

  if (tier1) {
    // QKV split-K=2: 768 half-K blocks = 3 full CU rounds
    gemm256<EPI_PART><<<768, 512, 0, stream>>>(h1, wbuf, M_, 3 * H_, H_,
                                               H_ / 128, p0, p1, nullptr);
    qkv_finish<<<(B_ * NH_ * L_ * 64) / 256, 256, 0, stream>>>(
        p0, p1, cosT, sinT, qb, kb, vb);
  } else {
    int nwg_qkv = (M_ / 256) * (3 * H_ / 256);   // 384
    gemm256<EPI_QKV3><<<nwg_qkv, 512, 0, stream>>>(h1, wbuf, M_, 3 * H_, H_,
                                                   H_ / 64, qb, nullptr, nullptr);
    int nrope = B_ * NH_ * L_ * 64;
    rope_apply<<<nrope / 256, 256, 0, stream>>>(qb, cosT, sinT);
    rope_apply<<<nrope / 256, 256, 0, stream>>>(kb, cosT, sinT);
  }

  vtrans_k<<<dim3(L_ / 64, D_ / 64, B_ * NH_), 256, 0, stream>>>(vb, vtb);
  flash_attn<<<dim3(L_ / 64, NH_, B_), 256, 0, stream>>>(qb, kb, vtb, attn);

  // weight conversions for WO (+ wd in tier1, into free p1) — one launch
  if (tier1) {
    cvt2<<<(nHH4 + nIH4) / 256 + 1, 256, 0, stream>>>(wo, wbuf, nHH4,
                                                      wd, wd_b, nIH4);
  } else {
    cvt_w<<<nHH4 / 256, 256, 0, stream>>>(wo, wbuf, nHH4);
  }
  // WO: split-K=2, partials kb/vb; fused reduce+residual+rmsnorm
  gemm256<EPI_PART><<<256, 512, 0, stream>>>(attn, wbuf, M_, H_, H_,
                                             H_ / 128, kb, vb, nullptr);
  reduce_rms<<<M_, 256, 0, stream>>>(kb, vb, x, ln2w, x2, h2);

  if (tier1 || tier2) {
    // fused gate+up: one pass, silu(g)*u in-register; one cvt launch
    cvt2<<<(2 * nIH4) / 256, 256, 0, stream>>>(wg, wbuf, nIH4, wu, wu_b, nIH4);
    int nwg_glu = (M_ / 256) * (I_ / 128);     // 1024
    gemm256<EPI_GLU><<<nwg_glu, 512, 0, stream>>>(h2, wbuf, M_, I_, H_,
                                                  H_ / 64, gateb, nullptr, wu_b);
  } else {
    int nwg256 = (M_ / 256) * (I_ / 256);
    cvt_w<<<nIH4 / 256, 256, 0, stream>>>(wg, wbuf, nIH4);
    gemm256<EPI_SILU><<<nwg256, 512, 0, stream>>>(h2, wbuf, M_, I_, H_,
                                                  H_ / 64, gateb, nullptr, nullptr);
    cvt_w<<<nIH4 / 256, 256, 0, stream>>>(wu, wbuf, nIH4);
    gemm256<EPI_MUL><<<nwg256, 512, 0, stream>>>(h2, wbuf, M_, I_, H_,
                                                 H_ / 64, gateb, nullptr, nullptr);
  }

  // down-proj: split-K=2, partials h1/attn, reduce adds residual x2 -> out
  u16* wdsrc;
  if (tier1) {
    wdsrc = wd_b;                      // already converted alongside wo
  } else {
    cvt_w<<<nIH4 / 256, 256, 0, stream>>>(wd, wbuf, nIH4);
    wdsrc = wbuf;
  }
  gemm256<EPI_PART><<<256, 512, 0, stream>>>(gateb, wdsrc, M_, H_, I_,
                                             I_ / 128, h1, attn, nullptr);
  down_reduce<<<MH4 / 256, 256, 0, stream>>>(h1, attn, x2, out, MH4);
}

// Round 19
// 811.494 us; speedup vs baseline: 1.0088x; 1.0088x over previous
//
#include <hip/hip_runtime.h>
#include <stdint.h>

#define B_ 2
#define L_ 2048
#define H_ 2048
#define NH_ 16
#define D_ 128
#define I_ 8192
#define M_ (B_*L_)

typedef unsigned short u16;
typedef __attribute__((ext_vector_type(8))) short bf16x8;
typedef __attribute__((ext_vector_type(4))) float f32x4;

__device__ __forceinline__ u16 f2bf(float f) {
  union { float f; uint32_t u; } c; c.f = f;
  return (u16)((c.u + 0x7fffu + ((c.u >> 16) & 1u)) >> 16);
}
__device__ __forceinline__ float bf2f(u16 h) {
  union { uint32_t u; float f; } c; c.u = ((uint32_t)h) << 16;
  return c.f;
}
// global -> LDS direct DMA, 16B/lane. LDS dest is wave-uniform base + lane*16.
__device__ __forceinline__ void gload16(const void* g, void* l) {
  __builtin_amdgcn_global_load_lds(
      (__attribute__((address_space(1))) void*)g,
      (__attribute__((address_space(3))) void*)l, 16, 0, 0);
}

// ---------------- fp32 -> bf16 conversion ----------------
__global__ void cvt_w(const float* __restrict__ src, u16* __restrict__ dst, int n4) {
  int i = blockIdx.x * blockDim.x + threadIdx.x;
  if (i >= n4) return;
  float4 v = ((const float4*)src)[i];
  ushort4 o;
  o.x = f2bf(v.x); o.y = f2bf(v.y); o.z = f2bf(v.z); o.w = f2bf(v.w);
  ((ushort4*)dst)[i] = o;
}

// ---- 2-region cvt, one launch ----
__global__ void cvt2(const float* __restrict__ s0, u16* __restrict__ d0, int n40,
                     const float* __restrict__ s1, u16* __restrict__ d1, int n41) {
  int i = blockIdx.x * blockDim.x + threadIdx.x;
  if (i < n40) {
    float4 v = ((const float4*)s0)[i];
    ushort4 o;
    o.x = f2bf(v.x); o.y = f2bf(v.y); o.z = f2bf(v.z); o.w = f2bf(v.w);
    ((ushort4*)d0)[i] = o;
  } else if (i < n40 + n41) {
    int j = i - n40;
    float4 v = ((const float4*)s1)[j];
    ushort4 o;
    o.x = f2bf(v.x); o.y = f2bf(v.y); o.z = f2bf(v.z); o.w = f2bf(v.w);
    ((ushort4*)d1)[j] = o;
  }
}

// ---- 3-region cvt (wq,wk,wv -> stacked dst), one launch ----
__global__ void cvt3(const float* __restrict__ s0, const float* __restrict__ s1,
                     const float* __restrict__ s2, u16* __restrict__ dst, int n4) {
  int i = blockIdx.x * blockDim.x + threadIdx.x;   // 3*n4 total
  int reg = i / n4, off = i % n4;
  const float* src = (reg == 0) ? s0 : (reg == 1) ? s1 : s2;
  float4 v = ((const float4*)src)[off];
  ushort4 o;
  o.x = f2bf(v.x); o.y = f2bf(v.y); o.z = f2bf(v.z); o.w = f2bf(v.w);
  ((ushort4*)(dst + (size_t)reg * H_ * H_))[off] = o;
}

// ---- split-K QKV finish: q/k/v = p0+p1, rope(q,k), scatter to (B,NH,L,D) ----
__global__ __launch_bounds__(256)
void qkv_finish(const u16* __restrict__ p0, const u16* __restrict__ p1,
                const float* __restrict__ cosT, const float* __restrict__ sinT,
                u16* __restrict__ qb, u16* __restrict__ kb, u16* __restrict__ vb) {
  int i = blockIdx.x * blockDim.x + threadIdx.x;  // B_*NH_*L_*64
  int d = i & 63;
  size_t row = (size_t)(i >> 6);          // (b*NH+h)*L + l
  int l = (int)(row & (L_ - 1));
  int h = (int)((row >> 11) & (NH_ - 1));
  int b = (int)(row >> 15);
  size_t bl = (size_t)b * L_ + l;
  const u16* r0 = p0 + bl * (3 * H_);
  const u16* r1 = p1 + bl * (3 * H_);
  int c = h * 128 + d;
  float cv = cosT[l * 64 + d], sv = sinT[l * 64 + d];
  float x1 = bf2f(r0[c]) + bf2f(r1[c]);
  float x2 = bf2f(r0[c + 64]) + bf2f(r1[c + 64]);
  u16* qp = qb + row * D_;
  qp[d]      = f2bf(x1 * cv - x2 * sv);
  qp[d + 64] = f2bf(x2 * cv + x1 * sv);
  x1 = bf2f(r0[c + 2048]) + bf2f(r1[c + 2048]);
  x2 = bf2f(r0[c + 2112]) + bf2f(r1[c + 2112]);
  u16* kp = kb + row * D_;
  kp[d]      = f2bf(x1 * cv - x2 * sv);
  kp[d + 64] = f2bf(x2 * cv + x1 * sv);
  u16* vp = vb + row * D_;
  vp[d]      = f2bf(bf2f(r0[c + 4096]) + bf2f(r1[c + 4096]));
  vp[d + 64] = f2bf(bf2f(r0[c + 4160]) + bf2f(r1[c + 4160]));
}

// ---------------- split-K partial reduce: out = p0 + p1 + res (fp32) --------
__global__ __launch_bounds__(256) void down_reduce(const u16* __restrict__ p0,
                                                   const u16* __restrict__ p1,
                                                   const float* __restrict__ res,
                                                   float* __restrict__ out, int n4) {
  int i = blockIdx.x * blockDim.x + threadIdx.x;
  if (i >= n4) return;
  ushort4 a = ((const ushort4*)p0)[i];
  ushort4 b = ((const ushort4*)p1)[i];
  float4 r = ((const float4*)res)[i];
  float4 o;
  o.x = bf2f(a.x) + bf2f(b.x) + r.x;
  o.y = bf2f(a.y) + bf2f(b.y) + r.y;
  o.z = bf2f(a.z) + bf2f(b.z) + r.z;
  o.w = bf2f(a.w) + bf2f(b.w) + r.w;
  ((float4*)out)[i] = o;
}

// ---- fused: x2 = p0+p1+res; h2 = rmsnorm(x2, w)  (one pass, block/row) ----
__global__ __launch_bounds__(256)
void reduce_rms(const u16* __restrict__ p0, const u16* __restrict__ p1,
                const float* __restrict__ res, const float* __restrict__ w,
                float* __restrict__ x2o, u16* __restrict__ h2o) {
  int row = blockIdx.x, t = threadIdx.x;
  size_t base = (size_t)row * H_;
  ushort4 a0 = ((const ushort4*)(p0 + base))[t * 2];
  ushort4 a1 = ((const ushort4*)(p0 + base))[t * 2 + 1];
  ushort4 b0 = ((const ushort4*)(p1 + base))[t * 2];
  ushort4 b1 = ((const ushort4*)(p1 + base))[t * 2 + 1];
  float4 r0 = ((const float4*)(res + base))[t * 2];
  float4 r1 = ((const float4*)(res + base))[t * 2 + 1];
  float4 v0, v1;
  v0.x = bf2f(a0.x) + bf2f(b0.x) + r0.x;
  v0.y = bf2f(a0.y) + bf2f(b0.y) + r0.y;
  v0.z = bf2f(a0.z) + bf2f(b0.z) + r0.z;
  v0.w = bf2f(a0.w) + bf2f(b0.w) + r0.w;
  v1.x = bf2f(a1.x) + bf2f(b1.x) + r1.x;
  v1.y = bf2f(a1.y) + bf2f(b1.y) + r1.y;
  v1.z = bf2f(a1.z) + bf2f(b1.z) + r1.z;
  v1.w = bf2f(a1.w) + bf2f(b1.w) + r1.w;
  ((float4*)(x2o + base))[t * 2] = v0;
  ((float4*)(x2o + base))[t * 2 + 1] = v1;
  float s = v0.x*v0.x + v0.y*v0.y + v0.z*v0.z + v0.w*v0.w
          + v1.x*v1.x + v1.y*v1.y + v1.z*v1.z + v1.w*v1.w;
  for (int m = 1; m < 64; m <<= 1) s += __shfl_xor(s, m);
  __shared__ float sm[4];
  if ((t & 63) == 0) sm[t >> 6] = s;
  __syncthreads();
  float tot = sm[0] + sm[1] + sm[2] + sm[3];
  float rs = rsqrtf(tot / (float)H_ + 1e-6f);
  const float4* wr = (const float4*)w;
  float4 w0 = wr[t * 2], w1 = wr[t * 2 + 1];
  ushort4 o0, o1;
  o0.x = f2bf(v0.x * rs * w0.x); o0.y = f2bf(v0.y * rs * w0.y);
  o0.z = f2bf(v0.z * rs * w0.z); o0.w = f2bf(v0.w * rs * w0.w);
  o1.x = f2bf(v1.x * rs * w1.x); o1.y = f2bf(v1.y * rs * w1.y);
  o1.z = f2bf(v1.z * rs * w1.z); o1.w = f2bf(v1.w * rs * w1.w);
  ((ushort4*)(h2o + base))[t * 2] = o0;
  ((ushort4*)(h2o + base))[t * 2 + 1] = o1;
}

// ---------------- RMSNorm: one block per row ----------------
__global__ __launch_bounds__(256) void rmsnorm_k(const float* __restrict__ x,
                                                 const float* __restrict__ w,
                                                 u16* __restrict__ out) {
  int row = blockIdx.x;
  int t = threadIdx.x;
  const float4* xr = (const float4*)(x + (size_t)row * H_);
  float4 a = xr[t * 2], b = xr[t * 2 + 1];
  float s = a.x*a.x + a.y*a.y + a.z*a.z + a.w*a.w
          + b.x*b.x + b.y*b.y + b.z*b.z + b.w*b.w;
  for (int m = 1; m < 64; m <<= 1) s += __shfl_xor(s, m);
  __shared__ float sm[4];
  if ((t & 63) == 0) sm[t >> 6] = s;
  __syncthreads();
  float tot = sm[0] + sm[1] + sm[2] + sm[3];
  float rs = rsqrtf(tot / (float)H_ + 1e-6f);
  const float4* wr = (const float4*)w;
  float4 w0 = wr[t * 2], w1 = wr[t * 2 + 1];
  ushort4 o0, o1;
  o0.x = f2bf(a.x * rs * w0.x); o0.y = f2bf(a.y * rs * w0.y);
  o0.z = f2bf(a.z * rs * w0.z); o0.w = f2bf(a.w * rs * w0.w);
  o1.x = f2bf(b.x * rs * w1.x); o1.y = f2bf(b.y * rs * w1.y);
  o1.z = f2bf(b.z * rs * w1.z); o1.w = f2bf(b.w * rs * w1.w);
  ushort4* orow = (ushort4*)(out + (size_t)row * H_);
  orow[t * 2] = o0; orow[t * 2 + 1] = o1;
}

// ---------------- RoPE tables ----------------
__global__ void rope_tab(float* __restrict__ cosT, float* __restrict__ sinT,
                         const int* __restrict__ offp) {
  int i = blockIdx.x * blockDim.x + threadIdx.x;  // L_*64
  int d = i & 63, l = i >> 6;
  float inv = powf(10000.0f, -(float)d / 64.0f);
  float ang = (float)(l + *offp) * inv;
  cosT[i] = cosf(ang);
  sinT[i] = sinf(ang);
}

// ---------------- RoPE apply, in-place on (B,NH,L,D) bf16 (fallback) --------
__global__ void rope_apply(u16* __restrict__ qk, const float* __restrict__ cosT,
                           const float* __restrict__ sinT) {
  int i = blockIdx.x * blockDim.x + threadIdx.x;  // B_*NH_*L_*64
  int d = i & 63;
  size_t row = (size_t)(i >> 6);
  int l = (int)(row & (L_ - 1));
  u16* p = qk + row * D_;
  float x1 = bf2f(p[d]), x2 = bf2f(p[d + 64]);
  float c = cosT[l * 64 + d], s = sinT[l * 64 + d];
  p[d]      = f2bf(x1 * c - x2 * s);
  p[d + 64] = f2bf(x2 * c + x1 * s);
}

// ---------------- V transpose: (B,NH,L,D) -> (B,NH,D,L) ----------------
__global__ __launch_bounds__(256) void vtrans_k(const u16* __restrict__ v,
                                                u16* __restrict__ vt) {
  __shared__ u16 tile[64][65];
  int l0 = blockIdx.x * 64, d0 = blockIdx.y * 64;
  size_t base = (size_t)blockIdx.z * L_ * D_;
  int t = threadIdx.x;
  int tr = t >> 3, tc = (t & 7) * 8;
  #pragma unroll
  for (int it = 0; it < 2; ++it) {
    int r = tr + it * 32;
    const u16* src = v + base + (size_t)(l0 + r) * D_ + d0 + tc;
    ushort4 u0 = ((const ushort4*)src)[0], u1 = ((const ushort4*)src)[1];
    tile[r][tc + 0] = u0.x; tile[r][tc + 1] = u0.y;
    tile[r][tc + 2] = u0.z; tile[r][tc + 3] = u0.w;
    tile[r][tc + 4] = u1.x; tile[r][tc + 5] = u1.y;
    tile[r][tc + 6] = u1.z; tile[r][tc + 7] = u1.w;
  }
  __syncthreads();
  #pragma unroll
  for (int it = 0; it < 2; ++it) {
    int r = tr + it * 32;
    u16* dst = vt + base + (size_t)(d0 + r) * L_ + l0 + tc;
    ushort4 o0, o1;
    o0.x = tile[tc + 0][r]; o0.y = tile[tc + 1][r];
    o0.z = tile[tc + 2][r]; o0.w = tile[tc + 3][r];
    o1.x = tile[tc + 4][r]; o1.y = tile[tc + 5][r];
    o1.z = tile[tc + 6][r]; o1.w = tile[tc + 7][r];
    ((ushort4*)dst)[0] = o0; ((ushort4*)dst)[1] = o1;
  }
}

#define EPI_SILU 1
#define EPI_MUL 2
#define EPI_PART 4
#define EPI_QKV3 5
#define EPI_GLU 6

// ---------------- GEMM 256x256 8-wave quadrant-phased (r9 structure) ---------
// FROZEN K-loop (r6/r8/r10 schedule variants null at MfmaUtil ~30-45%).
// 512 thr = 8 waves; BK=64; LDS 128KB dbuf; vmcnt(4) counted waits; XOR
// swizzle both-sides (rule #21); column-major wg->(m,n). NO tail-cvt (r15).
template <int EPI>
__global__ __launch_bounds__(512, 2)
void gemm256(const u16* __restrict__ A, const u16* __restrict__ Bw,
             int M, int N, int K, int nk,
             u16* __restrict__ outb, u16* __restrict__ outb2,
             const u16* __restrict__ Bw2) {
  __shared__ __attribute__((aligned(16))) u16 Asm[2][2][8192];
  __shared__ __attribute__((aligned(16))) u16 Bsm[2][2][8192];
  int tid = threadIdx.x;
  int wid = tid >> 6, lane = tid & 63;
  int r16 = lane & 15, g4 = lane >> 4;
  // bijective XCD swizzle (m204)
  int nwg = gridDim.x, bid = blockIdx.x;
  int q8 = nwg >> 3, r8 = nwg & 7, xcd = bid & 7, loc = bid >> 3;
  int wgall = (xcd < r8 ? xcd * (q8 + 1) : r8 * (q8 + 1) + (xcd - r8) * q8) + loc;
  int nwg_geo = (M >> 8) * ((EPI == EPI_GLU) ? (N >> 7) : (N >> 8));
  int ks = wgall / nwg_geo;     // split-K slice (EPI_PART)
  int wg = wgall % nwg_geo;
  int MX = M >> 8;
  int m0 = (wg % MX) * 256;     // column-major: m fastest
  int n0 = (wg / MX) * ((EPI == EPI_GLU) ? 128 : 256);
  const char* Ab = (const char*)(A + (size_t)ks * nk * 64);
  const char* Bb = (const char*)(Bw + (size_t)ks * nk * 64);
  const char* Bb2 = (const char*)Bw2;
  u16* ob = (EPI == EPI_PART && ks) ? outb2 : outb;

  f32x4 acc[2][2][4][2] = {};
  bf16x8 afr[4][2];      // A frags for current qm
  bf16x8 bfr[2][2][2];   // B frags [qn][nf][kk], both qn held

  // stage half sel of tile kt1: 0:A-h0 1:B-h0 2:B-h1 3:A-h1
  auto STAGE = [&](int kt1, int sel) {
    if (kt1 >= nk) return;
    int buf = kt1 & 1;
    int k0 = kt1 << 6;
    const char* gb; char* lb; int row0;
    if (sel == 0)      { gb = Ab; row0 = m0;       lb = (char*)&Asm[buf][0][0]; }
    else if (sel == 3) { gb = Ab; row0 = m0 + 128; lb = (char*)&Asm[buf][1][0]; }
    else if (sel == 1) { gb = Bb; row0 = n0;       lb = (char*)&Bsm[buf][0][0]; }
    else               { gb = (EPI == EPI_GLU) ? Bb2 : Bb;
                         row0 = (EPI == EPI_GLU) ? n0 : n0 + 128;
                         lb = (char*)&Bsm[buf][1][0]; }
    #pragma unroll
    for (int j = 0; j < 2; ++j) {
      int p = j * 8192 + wid * 1024 + lane * 16;
      int r = p >> 7;
      int cb = (p & 127) ^ ((r & 7) << 4);
      gload16(gb + ((size_t)(row0 + r) * K + k0) * 2 + cb,
              lb + j * 8192 + wid * 1024);
    }
  };

  // prologue: tile 0, order A0,B0,B1,A1 (8 loads in flight)
  STAGE(0, 0); STAGE(0, 1); STAGE(0, 2); STAGE(0, 3);

  const int QM[4] = {0, 0, 1, 1};
  const int QN[4] = {0, 1, 1, 0};

  for (int kt = 0; kt < nk; ++kt) {
    int cur = kt & 1;
    #pragma unroll
    for (int ph = 0; ph < 4; ++ph) {
      if (ph < 3) {
        __builtin_amdgcn_sched_barrier(0);
        asm volatile("s_waitcnt vmcnt(4)" ::: "memory");
      }
      __builtin_amdgcn_s_barrier();
      __builtin_amdgcn_sched_barrier(0);
      const int qm = QM[ph], qn = QN[ph];
      if (ph == 0 || ph == 2) {            // (re)load A frags for this qm
        const char* Ah = (const char*)&Asm[cur][qm][0];
        #pragma unroll
        for (int mf = 0; mf < 4; ++mf) {
          int R = (wid >> 2) * 64 + mf * 16 + r16;
          int sw = (R & 7) << 4;
          afr[mf][0] = *(const bf16x8*)(Ah + R * 128 + ((g4 * 16) ^ sw));
          afr[mf][1] = *(const bf16x8*)(Ah + R * 128 + ((64 + g4 * 16) ^ sw));
        }
      }
      if (ph == 0 || ph == 1) {            // load B frags for this qn
        const char* Bh = (const char*)&Bsm[cur][qn][0];
        #pragma unroll
        for (int nf = 0; nf < 2; ++nf) {
          int R = (wid & 3) * 32 + nf * 16 + r16;
          int sw = (R & 7) << 4;
          bfr[qn][nf][0] = *(const bf16x8*)(Bh + R * 128 + ((g4 * 16) ^ sw));
          bfr[qn][nf][1] = *(const bf16x8*)(Bh + R * 128 + ((64 + g4 * 16) ^ sw));
        }
      }
      STAGE(kt + 1, ph);                    // next tile, one half per phase
      __builtin_amdgcn_s_setprio(1);
      #pragma unroll
      for (int mf = 0; mf < 4; ++mf)
        #pragma unroll
        for (int nf = 0; nf < 2; ++nf)
          #pragma unroll
          for (int kk = 0; kk < 2; ++kk)
            acc[qm][qn][mf][nf] = __builtin_amdgcn_mfma_f32_16x16x32_bf16(
                afr[mf][kk], bfr[qn][nf][kk], acc[qm][qn][mf][nf], 0, 0, 0);
      __builtin_amdgcn_s_setprio(0);
    }
  }
  // epilogue
  if (EPI == EPI_GLU) {
    #pragma unroll
    for (int qm = 0; qm < 2; ++qm)
      #pragma unroll
      for (int mf = 0; mf < 4; ++mf)
        #pragma unroll
        for (int nf = 0; nf < 2; ++nf)
          #pragma unroll
          for (int rr = 0; rr < 4; ++rr) {
            int row = m0 + qm * 128 + (wid >> 2) * 64 + mf * 16 + g4 * 4 + rr;
            int col = n0 + (wid & 3) * 32 + nf * 16 + r16;
            float g = acc[qm][0][mf][nf][rr];
            float u = acc[qm][1][mf][nf][rr];
            float sg = g / (1.0f + __expf(-g));
            outb[(size_t)row * N + col] = f2bf(sg * u);
          }
    return;
  }
  #pragma unroll
  for (int qm = 0; qm < 2; ++qm)
    #pragma unroll
    for (int qn = 0; qn < 2; ++qn)
      #pragma unroll
      for (int mf = 0; mf < 4; ++mf)
        #pragma unroll
        for (int nf = 0; nf < 2; ++nf)
          #pragma unroll
          for (int rr = 0; rr < 4; ++rr) {
            int row = m0 + qm * 128 + (wid >> 2) * 64 + mf * 16 + g4 * 4 + rr;
            int col = n0 + qn * 128 + (wid & 3) * 32 + nf * 16 + r16;
            float val = acc[qm][qn][mf][nf][rr];
            if (EPI == EPI_SILU) {
              ob[(size_t)row * N + col] = f2bf(val / (1.0f + __expf(-val)));
            } else if (EPI == EPI_MUL) {
              float g = bf2f(ob[(size_t)row * N + col]);
              ob[(size_t)row * N + col] = f2bf(g * val);
            } else if (EPI == EPI_PART) {
              ob[(size_t)row * N + col] = f2bf(val);
            } else if (EPI == EPI_QKV3) {
              int which = col >> 11, within = col & 2047;
              int hh = within >> 7, d = within & 127;
              int bb = row >> 11, l = row & 2047;
              ob[(size_t)which * M_ * H_ +
                 ((((size_t)bb * NH_ + hh) * L_ + l) << 7) + d] = f2bf(val);
            }
          }
}

// ---------------- Flash attention (causal), QBLK=64, K/V dbuf (r17 exact) ----
// defer-max REVERTED (r18: +29µs regression — the per-row __all branch broke
// the softmax/store interleave in this structure; T13 is structure-dependent).
__global__ __launch_bounds__(256)
void flash_attn(const u16* __restrict__ q, const u16* __restrict__ k,
                const u16* __restrict__ vt, u16* __restrict__ out) {
  __shared__ __attribute__((aligned(16))) u16 Kt[2][64 * 128];
  __shared__ __attribute__((aligned(16))) u16 Vt[2][128 * 64];
  __shared__ __attribute__((aligned(16))) u16 Pl[4][16 * 64];
  int tid = threadIdx.x, w = tid >> 6, lane = tid & 63;
  int r16 = lane & 15, g4 = lane >> 4;
  int b = blockIdx.z, h = blockIdx.y;
  int qt = gridDim.x - 1 - blockIdx.x;   // longest blocks dispatch first
  int q0 = qt * 64;
  size_t bh = (size_t)b * NH_ + h;
  const char* qb = (const char*)(q + bh * L_ * D_);
  const char* kb = (const char*)(k + bh * L_ * D_);
  const char* vb = (const char*)(vt + bh * D_ * L_);
  int qrow = q0 + w * 16 + r16;
  bf16x8 qf[4];
  #pragma unroll
  for (int c = 0; c < 4; ++c)
    qf[c] = *(const bf16x8*)(qb + ((size_t)qrow * 128 + c * 32 + g4 * 8) * 2);
  f32x4 oacc[8] = {};
  float mrow[4], lsum[4];
  #pragma unroll
  for (int r = 0; r < 4; ++r) { mrow[r] = -3.0e38f; lsum[r] = 0.f; }
  int myq = q0 + w * 16 + g4 * 4;
  int ntiles = qt + 1;
  int rsw = (r16 & 7) << 4;
  const float sc = 0.08838834764831845f;

  auto STAGEKV = [&](int t, int buf) {
    if (t >= ntiles) return;
    int kv0 = t * 64;
    #pragma unroll
    for (int i = 0; i < 4; ++i) {
      int uoff = i * 4096 + w * 1024;
      int lin = uoff + lane * 16;
      int krow = lin >> 8;
      int kcol = (lin & 255) ^ ((krow & 7) << 4);
      gload16(kb + (size_t)(kv0 + krow) * 256 + kcol,
              (char*)&Kt[buf][0] + uoff);
      int vrow = lin >> 7;
      int vcol = (lin & 127) ^ ((vrow & 7) << 4);
      gload16(vb + (size_t)vrow * (L_ * 2) + kv0 * 2 + vcol,
              (char*)&Vt[buf][0] + uoff);
    }
  };

  STAGEKV(0, 0);
  __syncthreads();   // implicit vmcnt(0) drain before first compute

  for (int t = 0; t < ntiles; ++t) {
    int buf = t & 1;
    int kv0 = t * 64;
    STAGEKV(t + 1, buf ^ 1);   // prefetch next tile; lands during compute
    const char* Kb = (const char*)&Kt[buf][0];
    const char* Vb = (const char*)&Vt[buf][0];
    // S = Q K^T
    f32x4 s[4] = {};
    __builtin_amdgcn_s_setprio(1);
    #pragma unroll
    for (int c = 0; c < 4; ++c) {
      #pragma unroll
      for (int n = 0; n < 4; ++n) {
        bf16x8 kf = *(const bf16x8*)(Kb + (n * 16 + r16) * 256
                                     + ((c * 64 + g4 * 16) ^ rsw));
        s[n] = __builtin_amdgcn_mfma_f32_16x16x32_bf16(qf[c], kf, s[n], 0, 0, 0);
      }
    }
    __builtin_amdgcn_s_setprio(0);
    // scale + causal mask + online softmax
    #pragma unroll
    for (int r = 0; r < 4; ++r) {
      float rm = -3.0e38f;
      #pragma unroll
      for (int n = 0; n < 4; ++n) {
        float v = s[n][r] * sc;
        int kvi = kv0 + n * 16 + r16;
        if (kvi > myq + r) v = -3.0e38f;
        s[n][r] = v;
        rm = fmaxf(rm, v);
      }
      rm = fmaxf(rm, __shfl_xor(rm, 1));
      rm = fmaxf(rm, __shfl_xor(rm, 2));
      rm = fmaxf(rm, __shfl_xor(rm, 4));
      rm = fmaxf(rm, __shfl_xor(rm, 8));
      float mnew = fmaxf(mrow[r], rm);
      float alpha = __expf(mrow[r] - mnew);
      mrow[r] = mnew;
      lsum[r] *= alpha;
      #pragma unroll
      for (int nf = 0; nf < 8; ++nf) oacc[nf][r] *= alpha;
      int prow = g4 * 4 + r;
      int psw = (prow & 7) << 3;
      #pragma unroll
      for (int n = 0; n < 4; ++n) {
        float pv = __expf(s[n][r] - mnew);
        lsum[r] += pv;
        Pl[w][prow * 64 + ((n * 16 + r16) ^ psw)] = f2bf(pv);
      }
    }
    // wave-internal LDS visibility fence (guide rule #18)
    asm volatile("s_waitcnt lgkmcnt(0)" ::: "memory");
    __builtin_amdgcn_sched_barrier(0);
    // O += P V
    __builtin_amdgcn_s_setprio(1);
    #pragma unroll
    for (int kc = 0; kc < 2; ++kc) {
      bf16x8 pf = *(const bf16x8*)((const char*)&Pl[w][0] + r16 * 128
                                   + ((kc * 64 + g4 * 16) ^ rsw));
      #pragma unroll
      for (int nf = 0; nf < 8; ++nf) {
        bf16x8 vf = *(const bf16x8*)(Vb + (nf * 16 + r16) * 128
                                     + ((kc * 64 + g4 * 16) ^ rsw));
        oacc[nf] = __builtin_amdgcn_mfma_f32_16x16x32_bf16(pf, vf, oacc[nf], 0, 0, 0);
      }
    }
    __builtin_amdgcn_s_setprio(0);
    __syncthreads();   // drains prefetch (vmcnt(0)) + publishes buf^1
  }
  #pragma unroll
  for (int r = 0; r < 4; ++r) {
    float l = lsum[r];
    l += __shfl_xor(l, 1); l += __shfl_xor(l, 2);
    l += __shfl_xor(l, 4); l += __shfl_xor(l, 8);
    float inv = 1.0f / l;
    size_t orow = ((size_t)b * L_ + (myq + r)) * H_ + h * D_;
    #pragma unroll
    for (int nf = 0; nf < 8; ++nf)
      out[orow + nf * 16 + r16] = f2bf(oacc[nf][r] * inv);
  }
}

// ---------------- host orchestration ----------------
extern "C" void kernel_launch(void* const* d_in, const int* in_sizes, int n_in,
                              void* d_out, int out_size, void* d_ws, size_t ws_size,
                              hipStream_t stream) {
  (void)in_sizes; (void)n_in; (void)out_size;
  const float* x    = (const float*)d_in[0];
  const float* ln1w = (const float*)d_in[1];
  const float* ln2w = (const float*)d_in[2];
  const float* wq   = (const float*)d_in[3];
  const float* wk   = (const float*)d_in[4];
  const float* wv   = (const float*)d_in[5];
  const float* wo   = (const float*)d_in[6];
  const float* wg   = (const float*)d_in[7];
  const float* wu   = (const float*)d_in[8];
  const float* wd   = (const float*)d_in[9];
  const int*   offp = (const int*)d_in[11];
  float* out = (float*)d_out;

  char* p = (char*)d_ws;
  auto alloc = [&](size_t bytes) {
    char* r = p;
    p += (bytes + 255) & ~(size_t)255;
    return r;
  };
  const size_t HH = (size_t)H_ * H_, IH = (size_t)I_ * H_;
  u16* wbuf = (u16*)alloc(IH * 2);                  // 32 MB, reused
  u16* h1   = (u16*)alloc((size_t)M_ * H_ * 2);     // 16 MB (h2; down partial 0)
  u16* qb   = (u16*)alloc((size_t)M_ * H_ * 2);     // 16 MB (gateb after attn)
  u16* kb   = (u16*)alloc((size_t)M_ * H_ * 2);     // 16 MB (WO partial 0)
  u16* vb   = (u16*)alloc((size_t)M_ * H_ * 2);     // 16 MB (WO partial 1)
  u16* vtb  = (u16*)alloc((size_t)M_ * H_ * 2);     // 16 MB
  u16* attn = (u16*)alloc((size_t)M_ * H_ * 2);     // 16 MB (down partial 1)
  float* x2 = (float*)alloc((size_t)M_ * H_ * 4);   // 32 MB
  float* cosT = (float*)alloc((size_t)L_ * 64 * 4);
  float* sinT = (float*)alloc((size_t)L_ * 64 * 4);
  u16* h2    = h1;   // h1 dead after QKV GEMM
  u16* gateb = qb;   // qb..vtb region dead after flash_attn / WO
  size_t used_base = (size_t)(p - (char*)d_ws);
  size_t MB96 = 2 * (((size_t)M_ * 3 * H_ * 2 + 255) & ~(size_t)255);
  bool tier1 = (used_base + MB96) <= ws_size;
  bool tier2 = !tier1 && (used_base + IH * 2) <= ws_size;
  u16 *p0 = nullptr, *p1 = nullptr, *wu_b = nullptr, *wd_b = nullptr;
  if (tier1) {
    p0 = (u16*)alloc((size_t)M_ * 3 * H_ * 2);      // 48 MB
    p1 = (u16*)alloc((size_t)M_ * 3 * H_ * 2);      // 48 MB
    wu_b = p0;    // free after qkv_finish
    wd_b = p1;    // free after qkv_finish (48MB >= 32MB needed)
  } else if (tier2) {
    wu_b = (u16*)alloc(IH * 2);
  }

  const int nHH4 = (int)(HH / 4), nIH4 = (int)(IH / 4);
  const int MH4 = M_ * H_ / 4;

  rmsnorm_k<<<M_, 256, 0, stream>>>(x, ln1w, h1);
  rope_tab<<<(L_ * 64) / 256, 256, 0, stream>>>(cosT, sinT, offp);

  // QKV weights -> wbuf (stacked), one launch
  cvt3<<<3 * nHH4 / 256, 256, 0, stream>>>(wq, wk, wv, wbuf, nHH4);

  if (tier1) {
    // QKV split-K=2: 768 half-K blocks = 3 full CU rounds
    gemm256<EPI_PART><<<768, 512, 0, stream>>>(h1, wbuf, M_, 3 * H_, H_,
                                               H_ / 128, p0, p1, nullptr);
    qkv_finish<<<(B_ * NH_ * L_ * 64) / 256, 256, 0, stream>>>(
        p0, p1, cosT, sinT, qb, kb, vb);
  } else {
    int nwg_qkv = (M_ / 256) * (3 * H_ / 256);   // 384
    gemm256<EPI_QKV3><<<nwg_qkv, 512, 0, stream>>>(h1, wbuf, M_, 3 * H_, H_,
                                                   H_ / 64, qb, nullptr, nullptr);
    int nrope = B_ * NH_ * L_ * 64;
    rope_apply<<<nrope / 256, 256, 0, stream>>>(qb, cosT, sinT);
    rope_apply<<<nrope / 256, 256, 0, stream>>>(kb, cosT, sinT);
  }

  vtrans_k<<<dim3(L_ / 64, D_ / 64, B_ * NH_), 256, 0, stream>>>(vb, vtb);
  flash_attn<<<dim3(L_ / 64, NH_, B_), 256, 0, stream>>>(qb, kb, vtb, attn);

  // weight conversions for WO (+ wd in tier1, into free p1) — one launch
  if (tier1) {
    cvt2<<<(nHH4 + nIH4) / 256 + 1, 256, 0, stream>>>(wo, wbuf, nHH4,
                                                      wd, wd_b, nIH4);
  } else {
    cvt_w<<<nHH4 / 256, 256, 0, stream>>>(wo, wbuf, nHH4);
  }
  // WO: split-K=2, partials kb/vb; fused reduce+residual+rmsnorm
  gemm256<EPI_PART><<<256, 512, 0, stream>>>(attn, wbuf, M_, H_, H_,
                                             H_ / 128, kb, vb, nullptr);
  reduce_rms<<<M_, 256, 0, stream>>>(kb, vb, x, ln2w, x2, h2);

  if (tier1 || tier2) {
    // fused gate+up: one pass, silu(g)*u in-register; one cvt launch
    cvt2<<<(2 * nIH4) / 256, 256, 0, stream>>>(wg, wbuf, nIH4, wu, wu_b, nIH4);
    int nwg_glu = (M_ / 256) * (I_ / 128);     // 1024
    gemm256<EPI_GLU><<<nwg_glu, 512, 0, stream>>>(h2, wbuf, M_, I_, H_,
                                                  H_ / 64, gateb, nullptr, wu_b);
  } else {
    int nwg256 = (M_ / 256) * (I_ / 256);
    cvt_w<<<nIH4 / 256, 256, 0, stream>>>(wg, wbuf, nIH4);
    gemm256<EPI_SILU><<<nwg256, 512, 0, stream>>>(h2, wbuf, M_, I_, H_,
                                                  H_ / 64, gateb, nullptr, nullptr);
    cvt_w<<<nIH4 / 256, 256, 0, stream>>>(wu, wbuf, nIH4);
    gemm256<EPI_MUL><<<nwg256, 512, 0, stream>>>(h2, wbuf, M_, I_, H_,
                                                 H_ / 64, gateb, nullptr, nullptr);
  }

  // down-proj: split-K=2, partials h1/attn, reduce adds residual x2 -> out
  u16* wdsrc;
  if (tier1) {
    wdsrc = wd_b;                      // already converted alongside wo
  } else {
    cvt_w<<<nIH4 / 256, 256, 0, stream>>>(wd, wbuf, nIH4);
    wdsrc = wbuf;
  }
  gemm256<EPI_PART><<<256, 512, 0, stream>>>(gateb, wdsrc, M_, H_, I_,
                                             I_ / 128, h1, attn, nullptr);
  down_reduce<<<MH4 / 256, 256, 0, stream>>>(h1, attn, x2, out, MH4);
}

// Round 20
// 779.674 us; speedup vs baseline: 1.0500x; 1.0408x over previous
//
#include <hip/hip_runtime.h>
#include <stdint.h>

#define B_ 2
#define L_ 2048
#define H_ 2048
#define NH_ 16
#define D_ 128
#define I_ 8192
#define M_ (B_*L_)

typedef unsigned short u16;
typedef __attribute__((ext_vector_type(8))) short bf16x8;
typedef __attribute__((ext_vector_type(4))) float f32x4;

__device__ __forceinline__ u16 f2bf(float f) {
  union { float f; uint32_t u; } c; c.f = f;
  return (u16)((c.u + 0x7fffu + ((c.u >> 16) & 1u)) >> 16);
}
__device__ __forceinline__ float bf2f(u16 h) {
  union { uint32_t u; float f; } c; c.u = ((uint32_t)h) << 16;
  return c.f;
}
// global -> LDS direct DMA, 16B/lane. LDS dest is wave-uniform base + lane*16.
__device__ __forceinline__ void gload16(const void* g, void* l) {
  __builtin_amdgcn_global_load_lds(
      (__attribute__((address_space(1))) void*)g,
      (__attribute__((address_space(3))) void*)l, 16, 0, 0);
}

// ---------------- fp32 -> bf16 conversion ----------------
__global__ void cvt_w(const float* __restrict__ src, u16* __restrict__ dst, int n4) {
  int i = blockIdx.x * blockDim.x + threadIdx.x;
  if (i >= n4) return;
  float4 v = ((const float4*)src)[i];
  ushort4 o;
  o.x = f2bf(v.x); o.y = f2bf(v.y); o.z = f2bf(v.z); o.w = f2bf(v.w);
  ((ushort4*)dst)[i] = o;
}

// ---- 3-region cvt (wq,wk,wv -> stacked dst), one launch ----
__global__ void cvt3(const float* __restrict__ s0, const float* __restrict__ s1,
                     const float* __restrict__ s2, u16* __restrict__ dst, int n4) {
  int i = blockIdx.x * blockDim.x + threadIdx.x;   // 3*n4 total
  int reg = i / n4, off = i % n4;
  const float* src = (reg == 0) ? s0 : (reg == 1) ? s1 : s2;
  float4 v = ((const float4*)src)[off];
  ushort4 o;
  o.x = f2bf(v.x); o.y = f2bf(v.y); o.z = f2bf(v.z); o.w = f2bf(v.w);
  ((ushort4*)(dst + (size_t)reg * H_ * H_))[off] = o;
}

// ---- split-K QKV finish: q/k/v = p0+p1, rope(q,k), scatter to (B,NH,L,D) ----
__global__ __launch_bounds__(256)
void qkv_finish(const u16* __restrict__ p0, const u16* __restrict__ p1,
                const float* __restrict__ cosT, const float* __restrict__ sinT,
                u16* __restrict__ qb, u16* __restrict__ kb, u16* __restrict__ vb) {
  int i = blockIdx.x * blockDim.x + threadIdx.x;  // B_*NH_*L_*64
  int d = i & 63;
  size_t row = (size_t)(i >> 6);          // (b*NH+h)*L + l
  int l = (int)(row & (L_ - 1));
  int h = (int)((row >> 11) & (NH_ - 1));
  int b = (int)(row >> 15);
  size_t bl = (size_t)b * L_ + l;
  const u16* r0 = p0 + bl * (3 * H_);
  const u16* r1 = p1 + bl * (3 * H_);
  int c = h * 128 + d;
  float cv = cosT[l * 64 + d], sv = sinT[l * 64 + d];
  float x1 = bf2f(r0[c]) + bf2f(r1[c]);
  float x2 = bf2f(r0[c + 64]) + bf2f(r1[c + 64]);
  u16* qp = qb + row * D_;
  qp[d]      = f2bf(x1 * cv - x2 * sv);
  qp[d + 64] = f2bf(x2 * cv + x1 * sv);
  x1 = bf2f(r0[c + 2048]) + bf2f(r1[c + 2048]);
  x2 = bf2f(r0[c + 2112]) + bf2f(r1[c + 2112]);
  u16* kp = kb + row * D_;
  kp[d]      = f2bf(x1 * cv - x2 * sv);
  kp[d + 64] = f2bf(x2 * cv + x1 * sv);
  u16* vp = vb + row * D_;
  vp[d]      = f2bf(bf2f(r0[c + 4096]) + bf2f(r1[c + 4096]));
  vp[d + 64] = f2bf(bf2f(r0[c + 4160]) + bf2f(r1[c + 4160]));
}

// ---------------- split-K partial reduce: out = p0 + p1 + res (fp32) --------
__global__ __launch_bounds__(256) void down_reduce(const u16* __restrict__ p0,
                                                   const u16* __restrict__ p1,
                                                   const float* __restrict__ res,
                                                   float* __restrict__ out, int n4) {
  int i = blockIdx.x * blockDim.x + threadIdx.x;
  if (i >= n4) return;
  ushort4 a = ((const ushort4*)p0)[i];
  ushort4 b = ((const ushort4*)p1)[i];
  float4 r = ((const float4*)res)[i];
  float4 o;
  o.x = bf2f(a.x) + bf2f(b.x) + r.x;
  o.y = bf2f(a.y) + bf2f(b.y) + r.y;
  o.z = bf2f(a.z) + bf2f(b.z) + r.z;
  o.w = bf2f(a.w) + bf2f(b.w) + r.w;
  ((float4*)out)[i] = o;
}

// ---- fused: x2 = p0+p1+res; h2 = rmsnorm(x2, w)  (one pass, block/row) ----
__global__ __launch_bounds__(256)
void reduce_rms(const u16* __restrict__ p0, const u16* __restrict__ p1,
                const float* __restrict__ res, const float* __restrict__ w,
                float* __restrict__ x2o, u16* __restrict__ h2o) {
  int row = blockIdx.x, t = threadIdx.x;
  size_t base = (size_t)row * H_;
  ushort4 a0 = ((const ushort4*)(p0 + base))[t * 2];
  ushort4 a1 = ((const ushort4*)(p0 + base))[t * 2 + 1];
  ushort4 b0 = ((const ushort4*)(p1 + base))[t * 2];
  ushort4 b1 = ((const ushort4*)(p1 + base))[t * 2 + 1];
  float4 r0 = ((const float4*)(res + base))[t * 2];
  float4 r1 = ((const float4*)(res + base))[t * 2 + 1];
  float4 v0, v1;
  v0.x = bf2f(a0.x) + bf2f(b0.x) + r0.x;
  v0.y = bf2f(a0.y) + bf2f(b0.y) + r0.y;
  v0.z = bf2f(a0.z) + bf2f(b0.z) + r0.z;
  v0.w = bf2f(a0.w) + bf2f(b0.w) + r0.w;
  v1.x = bf2f(a1.x) + bf2f(b1.x) + r1.x;
  v1.y = bf2f(a1.y) + bf2f(b1.y) + r1.y;
  v1.z = bf2f(a1.z) + bf2f(b1.z) + r1.z;
  v1.w = bf2f(a1.w) + bf2f(b1.w) + r1.w;
  ((float4*)(x2o + base))[t * 2] = v0;
  ((float4*)(x2o + base))[t * 2 + 1] = v1;
  float s = v0.x*v0.x + v0.y*v0.y + v0.z*v0.z + v0.w*v0.w
          + v1.x*v1.x + v1.y*v1.y + v1.z*v1.z + v1.w*v1.w;
  for (int m = 1; m < 64; m <<= 1) s += __shfl_xor(s, m);
  __shared__ float sm[4];
  if ((t & 63) == 0) sm[t >> 6] = s;
  __syncthreads();
  float tot = sm[0] + sm[1] + sm[2] + sm[3];
  float rs = rsqrtf(tot / (float)H_ + 1e-6f);
  const float4* wr = (const float4*)w;
  float4 w0 = wr[t * 2], w1 = wr[t * 2 + 1];
  ushort4 o0, o1;
  o0.x = f2bf(v0.x * rs * w0.x); o0.y = f2bf(v0.y * rs * w0.y);
  o0.z = f2bf(v0.z * rs * w0.z); o0.w = f2bf(v0.w * rs * w0.w);
  o1.x = f2bf(v1.x * rs * w1.x); o1.y = f2bf(v1.y * rs * w1.y);
  o1.z = f2bf(v1.z * rs * w1.z); o1.w = f2bf(v1.w * rs * w1.w);
  ((ushort4*)(h2o + base))[t * 2] = o0;
  ((ushort4*)(h2o + base))[t * 2 + 1] = o1;
}

// ---------------- RMSNorm: one block per row ----------------
__global__ __launch_bounds__(256) void rmsnorm_k(const float* __restrict__ x,
                                                 const float* __restrict__ w,
                                                 u16* __restrict__ out) {
  int row = blockIdx.x;
  int t = threadIdx.x;
  const float4* xr = (const float4*)(x + (size_t)row * H_);
  float4 a = xr[t * 2], b = xr[t * 2 + 1];
  float s = a.x*a.x + a.y*a.y + a.z*a.z + a.w*a.w
          + b.x*b.x + b.y*b.y + b.z*b.z + b.w*b.w;
  for (int m = 1; m < 64; m <<= 1) s += __shfl_xor(s, m);
  __shared__ float sm[4];
  if ((t & 63) == 0) sm[t >> 6] = s;
  __syncthreads();
  float tot = sm[0] + sm[1] + sm[2] + sm[3];
  float rs = rsqrtf(tot / (float)H_ + 1e-6f);
  const float4* wr = (const float4*)w;
  float4 w0 = wr[t * 2], w1 = wr[t * 2 + 1];
  ushort4 o0, o1;
  o0.x = f2bf(a.x * rs * w0.x); o0.y = f2bf(a.y * rs * w0.y);
  o0.z = f2bf(a.z * rs * w0.z); o0.w = f2bf(a.w * rs * w0.w);
  o1.x = f2bf(b.x * rs * w1.x); o1.y = f2bf(b.y * rs * w1.y);
  o1.z = f2bf(b.z * rs * w1.z); o1.w = f2bf(b.w * rs * w1.w);
  ushort4* orow = (ushort4*)(out + (size_t)row * H_);
  orow[t * 2] = o0; orow[t * 2 + 1] = o1;
}

// ---------------- RoPE tables ----------------
__global__ void rope_tab(float* __restrict__ cosT, float* __restrict__ sinT,
                         const int* __restrict__ offp) {
  int i = blockIdx.x * blockDim.x + threadIdx.x;  // L_*64
  int d = i & 63, l = i >> 6;
  float inv = powf(10000.0f, -(float)d / 64.0f);
  float ang = (float)(l + *offp) * inv;
  cosT[i] = cosf(ang);
  sinT[i] = sinf(ang);
}

// ---------------- RoPE apply, in-place on (B,NH,L,D) bf16 (fallback) --------
__global__ void rope_apply(u16* __restrict__ qk, const float* __restrict__ cosT,
                           const float* __restrict__ sinT) {
  int i = blockIdx.x * blockDim.x + threadIdx.x;  // B_*NH_*L_*64
  int d = i & 63;
  size_t row = (size_t)(i >> 6);
  int l = (int)(row & (L_ - 1));
  u16* p = qk + row * D_;
  float x1 = bf2f(p[d]), x2 = bf2f(p[d + 64]);
  float c = cosT[l * 64 + d], s = sinT[l * 64 + d];
  p[d]      = f2bf(x1 * c - x2 * s);
  p[d + 64] = f2bf(x2 * c + x1 * s);
}

// ---------------- V transpose: (B,NH,L,D) -> (B,NH,D,L) ----------------
__global__ __launch_bounds__(256) void vtrans_k(const u16* __restrict__ v,
                                                u16* __restrict__ vt) {
  __shared__ u16 tile[64][65];
  int l0 = blockIdx.x * 64, d0 = blockIdx.y * 64;
  size_t base = (size_t)blockIdx.z * L_ * D_;
  int t = threadIdx.x;
  int tr = t >> 3, tc = (t & 7) * 8;
  #pragma unroll
  for (int it = 0; it < 2; ++it) {
    int r = tr + it * 32;
    const u16* src = v + base + (size_t)(l0 + r) * D_ + d0 + tc;
    ushort4 u0 = ((const ushort4*)src)[0], u1 = ((const ushort4*)src)[1];
    tile[r][tc + 0] = u0.x; tile[r][tc + 1] = u0.y;
    tile[r][tc + 2] = u0.z; tile[r][tc + 3] = u0.w;
    tile[r][tc + 4] = u1.x; tile[r][tc + 5] = u1.y;
    tile[r][tc + 6] = u1.z; tile[r][tc + 7] = u1.w;
  }
  __syncthreads();
  #pragma unroll
  for (int it = 0; it < 2; ++it) {
    int r = tr + it * 32;
    u16* dst = vt + base + (size_t)(d0 + r) * L_ + l0 + tc;
    ushort4 o0, o1;
    o0.x = tile[tc + 0][r]; o0.y = tile[tc + 1][r];
    o0.z = tile[tc + 2][r]; o0.w = tile[tc + 3][r];
    o1.x = tile[tc + 4][r]; o1.y = tile[tc + 5][r];
    o1.z = tile[tc + 6][r]; o1.w = tile[tc + 7][r];
    ((ushort4*)dst)[0] = o0; ((ushort4*)dst)[1] = o1;
  }
}

#define EPI_SILU 1
#define EPI_MUL 2
#define EPI_PART 4
#define EPI_QKV3 5
#define EPI_GLU 6

// ---------------- GEMM 256x256 8-wave quadrant-phased (r9 structure) ---------
// FROZEN K-loop (r6/r8/r10 schedule variants null at MfmaUtil ~30-45%).
// 512 thr = 8 waves; BK=64; LDS 128KB dbuf; vmcnt(4) counted waits; XOR
// swizzle both-sides (rule #21); column-major wg->(m,n). NO tail-cvt (r15).
template <int EPI>
__global__ __launch_bounds__(512, 2)
void gemm256(const u16* __restrict__ A, const u16* __restrict__ Bw,
             int M, int N, int K, int nk,
             u16* __restrict__ outb, u16* __restrict__ outb2,
             const u16* __restrict__ Bw2) {
  __shared__ __attribute__((aligned(16))) u16 Asm[2][2][8192];
  __shared__ __attribute__((aligned(16))) u16 Bsm[2][2][8192];
  int tid = threadIdx.x;
  int wid = tid >> 6, lane = tid & 63;
  int r16 = lane & 15, g4 = lane >> 4;
  // bijective XCD swizzle (m204)
  int nwg = gridDim.x, bid = blockIdx.x;
  int q8 = nwg >> 3, r8 = nwg & 7, xcd = bid & 7, loc = bid >> 3;
  int wgall = (xcd < r8 ? xcd * (q8 + 1) : r8 * (q8 + 1) + (xcd - r8) * q8) + loc;
  int nwg_geo = (M >> 8) * ((EPI == EPI_GLU) ? (N >> 7) : (N >> 8));
  int ks = wgall / nwg_geo;     // split-K slice (EPI_PART)
  int wg = wgall % nwg_geo;
  int MX = M >> 8;
  int m0 = (wg % MX) * 256;     // column-major: m fastest
  int n0 = (wg / MX) * ((EPI == EPI_GLU) ? 128 : 256);
  const char* Ab = (const char*)(A + (size_t)ks * nk * 64);
  const char* Bb = (const char*)(Bw + (size_t)ks * nk * 64);
  const char* Bb2 = (const char*)Bw2;
  u16* ob = (EPI == EPI_PART && ks) ? outb2 : outb;

  f32x4 acc[2][2][4][2] = {};
  bf16x8 afr[4][2];      // A frags for current qm
  bf16x8 bfr[2][2][2];   // B frags [qn][nf][kk], both qn held

  // stage half sel of tile kt1: 0:A-h0 1:B-h0 2:B-h1 3:A-h1
  auto STAGE = [&](int kt1, int sel) {
    if (kt1 >= nk) return;
    int buf = kt1 & 1;
    int k0 = kt1 << 6;
    const char* gb; char* lb; int row0;
    if (sel == 0)      { gb = Ab; row0 = m0;       lb = (char*)&Asm[buf][0][0]; }
    else if (sel == 3) { gb = Ab; row0 = m0 + 128; lb = (char*)&Asm[buf][1][0]; }
    else if (sel == 1) { gb = Bb; row0 = n0;       lb = (char*)&Bsm[buf][0][0]; }
    else               { gb = (EPI == EPI_GLU) ? Bb2 : Bb;
                         row0 = (EPI == EPI_GLU) ? n0 : n0 + 128;
                         lb = (char*)&Bsm[buf][1][0]; }
    #pragma unroll
    for (int j = 0; j < 2; ++j) {
      int p = j * 8192 + wid * 1024 + lane * 16;
      int r = p >> 7;
      int cb = (p & 127) ^ ((r & 7) << 4);
      gload16(gb + ((size_t)(row0 + r) * K + k0) * 2 + cb,
              lb + j * 8192 + wid * 1024);
    }
  };

  // prologue: tile 0, order A0,B0,B1,A1 (8 loads in flight)
  STAGE(0, 0); STAGE(0, 1); STAGE(0, 2); STAGE(0, 3);

  const int QM[4] = {0, 0, 1, 1};
  const int QN[4] = {0, 1, 1, 0};

  for (int kt = 0; kt < nk; ++kt) {
    int cur = kt & 1;
    #pragma unroll
    for (int ph = 0; ph < 4; ++ph) {
      if (ph < 3) {
        __builtin_amdgcn_sched_barrier(0);
        asm volatile("s_waitcnt vmcnt(4)" ::: "memory");
      }
      __builtin_amdgcn_s_barrier();
      __builtin_amdgcn_sched_barrier(0);
      const int qm = QM[ph], qn = QN[ph];
      if (ph == 0 || ph == 2) {            // (re)load A frags for this qm
        const char* Ah = (const char*)&Asm[cur][qm][0];
        #pragma unroll
        for (int mf = 0; mf < 4; ++mf) {
          int R = (wid >> 2) * 64 + mf * 16 + r16;
          int sw = (R & 7) << 4;
          afr[mf][0] = *(const bf16x8*)(Ah + R * 128 + ((g4 * 16) ^ sw));
          afr[mf][1] = *(const bf16x8*)(Ah + R * 128 + ((64 + g4 * 16) ^ sw));
        }
      }
      if (ph == 0 || ph == 1) {            // load B frags for this qn
        const char* Bh = (const char*)&Bsm[cur][qn][0];
        #pragma unroll
        for (int nf = 0; nf < 2; ++nf) {
          int R = (wid & 3) * 32 + nf * 16 + r16;
          int sw = (R & 7) << 4;
          bfr[qn][nf][0] = *(const bf16x8*)(Bh + R * 128 + ((g4 * 16) ^ sw));
          bfr[qn][nf][1] = *(const bf16x8*)(Bh + R * 128 + ((64 + g4 * 16) ^ sw));
        }
      }
      STAGE(kt + 1, ph);                    // next tile, one half per phase
      __builtin_amdgcn_s_setprio(1);
      #pragma unroll
      for (int mf = 0; mf < 4; ++mf)
        #pragma unroll
        for (int nf = 0; nf < 2; ++nf)
          #pragma unroll
          for (int kk = 0; kk < 2; ++kk)
            acc[qm][qn][mf][nf] = __builtin_amdgcn_mfma_f32_16x16x32_bf16(
                afr[mf][kk], bfr[qn][nf][kk], acc[qm][qn][mf][nf], 0, 0, 0);
      __builtin_amdgcn_s_setprio(0);
    }
  }
  // epilogue
  if (EPI == EPI_GLU) {
    #pragma unroll
    for (int qm = 0; qm < 2; ++qm)
      #pragma unroll
      for (int mf = 0; mf < 4; ++mf)
        #pragma unroll
        for (int nf = 0; nf < 2; ++nf)
          #pragma unroll
          for (int rr = 0; rr < 4; ++rr) {
            int row = m0 + qm * 128 + (wid >> 2) * 64 + mf * 16 + g4 * 4 + rr;
            int col = n0 + (wid & 3) * 32 + nf * 16 + r16;
            float g = acc[qm][0][mf][nf][rr];
            float u = acc[qm][1][mf][nf][rr];
            float sg = g / (1.0f + __expf(-g));
            outb[(size_t)row * N + col] = f2bf(sg * u);
          }
    return;
  }
  #pragma unroll
  for (int qm = 0; qm < 2; ++qm)
    #pragma unroll
    for (int qn = 0; qn < 2; ++qn)
      #pragma unroll
      for (int mf = 0; mf < 4; ++mf)
        #pragma unroll
        for (int nf = 0; nf < 2; ++nf)
          #pragma unroll
          for (int rr = 0; rr < 4; ++rr) {
            int row = m0 + qm * 128 + (wid >> 2) * 64 + mf * 16 + g4 * 4 + rr;
            int col = n0 + qn * 128 + (wid & 3) * 32 + nf * 16 + r16;
            float val = acc[qm][qn][mf][nf][rr];
            if (EPI == EPI_SILU) {
              ob[(size_t)row * N + col] = f2bf(val / (1.0f + __expf(-val)));
            } else if (EPI == EPI_MUL) {
              float g = bf2f(ob[(size_t)row * N + col]);
              ob[(size_t)row * N + col] = f2bf(g * val);
            } else if (EPI == EPI_PART) {
              ob[(size_t)row * N + col] = f2bf(val);
            } else if (EPI == EPI_QKV3) {
              int which = col >> 11, within = col & 2047;
              int hh = within >> 7, d = within & 127;
              int bb = row >> 11, l = row & 2047;
              ob[(size_t)which * M_ * H_ +
                 ((((size_t)bb * NH_ + hh) * L_ + l) << 7) + d] = f2bf(val);
            }
          }
}

// ---------------- Flash attention (causal), QBLK=64, K/V dbuf (r12 best) ----
__global__ __launch_bounds__(256)
void flash_attn(const u16* __restrict__ q, const u16* __restrict__ k,
                const u16* __restrict__ vt, u16* __restrict__ out) {
  __shared__ __attribute__((aligned(16))) u16 Kt[2][64 * 128];
  __shared__ __attribute__((aligned(16))) u16 Vt[2][128 * 64];
  __shared__ __attribute__((aligned(16))) u16 Pl[4][16 * 64];
  int tid = threadIdx.x, w = tid >> 6, lane = tid & 63;
  int r16 = lane & 15, g4 = lane >> 4;
  int b = blockIdx.z, h = blockIdx.y;
  int qt = gridDim.x - 1 - blockIdx.x;   // longest blocks dispatch first
  int q0 = qt * 64;
  size_t bh = (size_t)b * NH_ + h;
  const char* qb = (const char*)(q + bh * L_ * D_);
  const char* kb = (const char*)(k + bh * L_ * D_);
  const char* vb = (const char*)(vt + bh * D_ * L_);
  int qrow = q0 + w * 16 + r16;
  bf16x8 qf[4];
  #pragma unroll
  for (int c = 0; c < 4; ++c)
    qf[c] = *(const bf16x8*)(qb + ((size_t)qrow * 128 + c * 32 + g4 * 8) * 2);
  f32x4 oacc[8] = {};
  float mrow[4], lsum[4];
  #pragma unroll
  for (int r = 0; r < 4; ++r) { mrow[r] = -3.0e38f; lsum[r] = 0.f; }
  int myq = q0 + w * 16 + g4 * 4;
  int ntiles = qt + 1;
  int rsw = (r16 & 7) << 4;
  const float sc = 0.08838834764831845f;

  auto STAGEKV = [&](int t, int buf) {
    if (t >= ntiles) return;
    int kv0 = t * 64;
    #pragma unroll
    for (int i = 0; i < 4; ++i) {
      int uoff = i * 4096 + w * 1024;
      int lin = uoff + lane * 16;
      int krow = lin >> 8;
      int kcol = (lin & 255) ^ ((krow & 7) << 4);
      gload16(kb + (size_t)(kv0 + krow) * 256 + kcol,
              (char*)&Kt[buf][0] + uoff);
      int vrow = lin >> 7;
      int vcol = (lin & 127) ^ ((vrow & 7) << 4);
      gload16(vb + (size_t)vrow * (L_ * 2) + kv0 * 2 + vcol,
              (char*)&Vt[buf][0] + uoff);
    }
  };

  STAGEKV(0, 0);
  __syncthreads();   // implicit vmcnt(0) drain before first compute

  for (int t = 0; t < ntiles; ++t) {
    int buf = t & 1;
    int kv0 = t * 64;
    STAGEKV(t + 1, buf ^ 1);   // prefetch next tile; lands during compute
    const char* Kb = (const char*)&Kt[buf][0];
    const char* Vb = (const char*)&Vt[buf][0];
    // S = Q K^T
    f32x4 s[4] = {};
    __builtin_amdgcn_s_setprio(1);
    #pragma unroll
    for (int c = 0; c < 4; ++c) {
      #pragma unroll
      for (int n = 0; n < 4; ++n) {
        bf16x8 kf = *(const bf16x8*)(Kb + (n * 16 + r16) * 256
                                     + ((c * 64 + g4 * 16) ^ rsw));
        s[n] = __builtin_amdgcn_mfma_f32_16x16x32_bf16(qf[c], kf, s[n], 0, 0, 0);
      }
    }
    __builtin_amdgcn_s_setprio(0);
    // scale + causal mask + online softmax
    #pragma unroll
    for (int r = 0; r < 4; ++r) {
      float rm = -3.0e38f;
      #pragma unroll
      for (int n = 0; n < 4; ++n) {
        float v = s[n][r] * sc;
        int kvi = kv0 + n * 16 + r16;
        if (kvi > myq + r) v = -3.0e38f;
        s[n][r] = v;
        rm = fmaxf(rm, v);
      }
      rm = fmaxf(rm, __shfl_xor(rm, 1));
      rm = fmaxf(rm, __shfl_xor(rm, 2));
      rm = fmaxf(rm, __shfl_xor(rm, 4));
      rm = fmaxf(rm, __shfl_xor(rm, 8));
      float mnew = fmaxf(mrow[r], rm);
      float alpha = __expf(mrow[r] - mnew);
      mrow[r] = mnew;
      lsum[r] *= alpha;
      #pragma unroll
      for (int nf = 0; nf < 8; ++nf) oacc[nf][r] *= alpha;
      int prow = g4 * 4 + r;
      int psw = (prow & 7) << 3;
      #pragma unroll
      for (int n = 0; n < 4; ++n) {
        float pv = __expf(s[n][r] - mnew);
        lsum[r] += pv;
        Pl[w][prow * 64 + ((n * 16 + r16) ^ psw)] = f2bf(pv);
      }
    }
    // wave-internal LDS visibility fence (guide rule #18)
    asm volatile("s_waitcnt lgkmcnt(0)" ::: "memory");
    __builtin_amdgcn_sched_barrier(0);
    // O += P V
    __builtin_amdgcn_s_setprio(1);
    #pragma unroll
    for (int kc = 0; kc < 2; ++kc) {
      bf16x8 pf = *(const bf16x8*)((const char*)&Pl[w][0] + r16 * 128
                                   + ((kc * 64 + g4 * 16) ^ rsw));
      #pragma unroll
      for (int nf = 0; nf < 8; ++nf) {
        bf16x8 vf = *(const bf16x8*)(Vb + (nf * 16 + r16) * 128
                                     + ((kc * 64 + g4 * 16) ^ rsw));
        oacc[nf] = __builtin_amdgcn_mfma_f32_16x16x32_bf16(pf, vf, oacc[nf], 0, 0, 0);
      }
    }
    __builtin_amdgcn_s_setprio(0);
    __syncthreads();   // drains prefetch (vmcnt(0)) + publishes buf^1
  }
  #pragma unroll
  for (int r = 0; r < 4; ++r) {
    float l = lsum[r];
    l += __shfl_xor(l, 1); l += __shfl_xor(l, 2);
    l += __shfl_xor(l, 4); l += __shfl_xor(l, 8);
    float inv = 1.0f / l;
    size_t orow = ((size_t)b * L_ + (myq + r)) * H_ + h * D_;
    #pragma unroll
    for (int nf = 0; nf < 8; ++nf)
      out[orow + nf * 16 + r16] = f2bf(oacc[nf][r] * inv);
  }
}

// ---------------- host orchestration (r16 exact — best measured, 790µs) -----
extern "C" void kernel_launch(void* const* d_in, const int* in_sizes, int n_in,
                              void* d_out, int out_size, void* d_ws, size_t ws_size,
                              hipStream_t stream) {
  (void)in_sizes; (void)n_in; (void)out_size;
  const float* x    = (const float*)d_in[0];
  const float* ln1w = (const float*)d_in[1];
  const float* ln2w = (const float*)d_in[2];
  const float* wq   = (const float*)d_in[3];
  const float* wk   = (const float*)d_in[4];
  const float* wv   = (const float*)d_in[5];
  const float* wo   = (const float*)d_in[6];
  const float* wg   = (const float*)d_in[7];
  const float* wu   = (const float*)d_in[8];
  const float* wd   = (const float*)d_in[9];
  const int*   offp = (const int*)d_in[11];
  float* out = (float*)d_out;

  char* p = (char*)d_ws;
  auto alloc = [&](size_t bytes) {
    char* r = p;
    p += (bytes + 255) & ~(size_t)255;
    return r;
  };
  const size_t HH = (size_t)H_ * H_, IH = (size_t)I_ * H_;
  u16* wbuf = (u16*)alloc(IH * 2);                  // 32 MB, reused
  u16* h1   = (u16*)alloc((size_t)M_ * H_ * 2);     // 16 MB (h2; down partial 0)
  u16* qb   = (u16*)alloc((size_t)M_ * H_ * 2);     // 16 MB (gateb after attn)
  u16* kb   = (u16*)alloc((size_t)M_ * H_ * 2);     // 16 MB (WO partial 0)
  u16* vb   = (u16*)alloc((size_t)M_ * H_ * 2);     // 16 MB (WO partial 1)
  u16* vtb  = (u16*)alloc((size_t)M_ * H_ * 2);     // 16 MB
  u16* attn = (u16*)alloc((size_t)M_ * H_ * 2);     // 16 MB (down partial 1)
  float* x2 = (float*)alloc((size_t)M_ * H_ * 4);   // 32 MB
  float* cosT = (float*)alloc((size_t)L_ * 64 * 4);
  float* sinT = (float*)alloc((size_t)L_ * 64 * 4);
  u16* h2    = h1;   // h1 dead after QKV GEMM
  u16* gateb = qb;   // qb..vtb region dead after flash_attn / WO
  size_t used_base = (size_t)(p - (char*)d_ws);
  size_t MB96 = 2 * (((size_t)M_ * 3 * H_ * 2 + 255) & ~(size_t)255);
  bool tier1 = (used_base + MB96) <= ws_size;
  bool tier2 = !tier1 && (used_base + IH * 2) <= ws_size;
  u16 *p0 = nullptr, *p1 = nullptr, *wu_b = nullptr;
  if (tier1) {
    p0 = (u16*)alloc((size_t)M_ * 3 * H_ * 2);      // 48 MB
    p1 = (u16*)alloc((size_t)M_ * 3 * H_ * 2);      // 48 MB
    wu_b = p0;                                       // reused after qkv_finish
  } else if (tier2) {
    wu_b = (u16*)alloc(IH * 2);
  }

  const int nHH4 = (int)(HH / 4), nIH4 = (int)(IH / 4);
  const int MH4 = M_ * H_ / 4;

  rmsnorm_k<<<M_, 256, 0, stream>>>(x, ln1w, h1);
  rope_tab<<<(L_ * 64) / 256, 256, 0, stream>>>(cosT, sinT, offp);

  // QKV weights -> wbuf (stacked), one launch
  cvt3<<<3 * nHH4 / 256, 256, 0, stream>>>(wq, wk, wv, wbuf, nHH4);

  if (tier1) {
    // QKV split-K=2: 768 half-K blocks = 3 full CU rounds
    gemm256<EPI_PART><<<768, 512, 0, stream>>>(h1, wbuf, M_, 3 * H_, H_,
                                               H_ / 128, p0, p1, nullptr);
    qkv_finish<<<(B_ * NH_ * L_ * 64) / 256, 256, 0, stream>>>(
        p0, p1, cosT, sinT, qb, kb, vb);
  } else {
    int nwg_qkv = (M_ / 256) * (3 * H_ / 256);   // 384
    gemm256<EPI_QKV3><<<nwg_qkv, 512, 0, stream>>>(h1, wbuf, M_, 3 * H_, H_,
                                                   H_ / 64, qb, nullptr, nullptr);
    int nrope = B_ * NH_ * L_ * 64;
    rope_apply<<<nrope / 256, 256, 0, stream>>>(qb, cosT, sinT);
    rope_apply<<<nrope / 256, 256, 0, stream>>>(kb, cosT, sinT);
  }

  vtrans_k<<<dim3(L_ / 64, D_ / 64, B_ * NH_), 256, 0, stream>>>(vb, vtb);
  flash_attn<<<dim3(L_ / 64, NH_, B_), 256, 0, stream>>>(qb, kb, vtb, attn);

  // WO: split-K=2, partials kb/vb; fused reduce+residual+rmsnorm
  cvt_w<<<nHH4 / 256, 256, 0, stream>>>(wo, wbuf, nHH4);
  gemm256<EPI_PART><<<256, 512, 0, stream>>>(attn, wbuf, M_, H_, H_,
                                             H_ / 128, kb, vb, nullptr);
  reduce_rms<<<M_, 256, 0, stream>>>(kb, vb, x, ln2w, x2, h2);

  if (tier1 || tier2) {
    // fused gate+up: one pass, silu(g)*u in-register (no RMW traffic)
    cvt_w<<<nIH4 / 256, 256, 0, stream>>>(wg, wbuf, nIH4);
    cvt_w<<<nIH4 / 256, 256, 0, stream>>>(wu, wu_b, nIH4);
    int nwg_glu = (M_ / 256) * (I_ / 128);     // 1024
    gemm256<EPI_GLU><<<nwg_glu, 512, 0, stream>>>(h2, wbuf, M_, I_, H_,
                                                  H_ / 64, gateb, nullptr, wu_b);
  } else {
    int nwg256 = (M_ / 256) * (I_ / 256);
    cvt_w<<<nIH4 / 256, 256, 0, stream>>>(wg, wbuf, nIH4);
    gemm256<EPI_SILU><<<nwg256, 512, 0, stream>>>(h2, wbuf, M_, I_, H_,
                                                  H_ / 64, gateb, nullptr, nullptr);
    cvt_w<<<nIH4 / 256, 256, 0, stream>>>(wu, wbuf, nIH4);
    gemm256<EPI_MUL><<<nwg256, 512, 0, stream>>>(h2, wbuf, M_, I_, H_,
                                                 H_ / 64, gateb, nullptr, nullptr);
  }

  // down-proj: split-K=2, partials h1/attn, reduce adds residual x2 -> out
  cvt_w<<<nIH4 / 256, 256, 0, stream>>>(wd, wbuf, nIH4);
  gemm256<EPI_PART><<<256, 512, 0, stream>>>(gateb, wbuf, M_, H_, I_,
                                             I_ / 128, h1, attn, nullptr);
  down_reduce<<<MH4 / 256, 256, 0, stream>>>(h1, attn, x2, out, MH4);
}